// Round 4
// baseline (2728.188 us; speedup 1.0000x reference)
//
#include <hip/hip_runtime.h>
#include <hip/hip_bf16.h>

typedef __hip_bfloat16 bf16;

#define N_DOC   10000
#define N_WORD  20000
#define N_ENT   10000
#define N_POS   60
#define DD      128
#define D_WEMB  300
#define E11     320000
#define E22     160000
#define E33     3600
#define E01     300000
#define E02     100000
#define E03     150000

// Runtime dtype flag (ws[0]): 1 if float inputs are packed bf16, 0 if fp32.
__device__ __forceinline__ float loadf(const void* p, size_t i, int isb) {
    return isb ? __bfloat162float(((const bf16*)p)[i])
               : ((const float*)p)[i];
}

// Detect input dtype from a randn fp32-or-bf16 buffer: fp32 words are "sane"
// (|x| in [1e-10,1e10]); bf16-packed words have exponent field >= 0xF6 for any
// |elem| >= 2^-63 -> |x| >= 2^119 or NaN/Inf -> "insane".
__global__ void detect_kernel(const unsigned* __restrict__ probe, int* __restrict__ flag) {
    __shared__ int cnt;
    if (threadIdx.x == 0) cnt = 0;
    __syncthreads();
    int insane = 0;
    for (int i = threadIdx.x; i < 1024; i += 256) {
        float x = __uint_as_float(probe[i]);
        float a = fabsf(x);
        if (!(a > 1e-10f && a < 1e10f)) insane++;   // NaN compares false -> insane
    }
    atomicAdd(&cnt, insane);
    __syncthreads();
    if (threadIdx.x == 0) *flag = (cnt > 512) ? 1 : 0;
}

// dst[rows[e], doff+0..d) += vals[e] * act(src[cols[e], 0..d)); one wave/edge.
// src_flagged: 1 -> src dtype follows *dflag (model input); 0 -> fp32 ws buffer.
template<bool RELU>
__global__ void spmm_kernel(const int* __restrict__ rows, const int* __restrict__ cols,
                            const void* __restrict__ vals,
                            const void* __restrict__ src, int sstride, int src_flagged,
                            float* __restrict__ dst, int dstride, int doff,
                            int d, int nE, const int* __restrict__ dflag) {
    int e = blockIdx.x * (blockDim.x >> 6) + (threadIdx.x >> 6);
    if (e >= nE) return;
    int isb  = *dflag;
    int sisb = src_flagged ? isb : 0;
    int lane = threadIdx.x & 63;
    int r = rows[e];
    int c = cols[e];
    float v = loadf(vals, e, isb);
    size_t sbase = (size_t)c * sstride;
    float* dp = dst + (size_t)r * dstride + doff;
    for (int j = lane; j < d; j += 64) {
        float x = loadf(src, sbase + j, sisb);
        if (RELU) x = fmaxf(x, 0.0f);
        atomicAdd(dp + j, v * x);
    }
}

// out[n x 128] = act(X[n x K]) @ W[K x 128] + b.  W staged fp32 in LDS.
// block = 128 threads (thread j = out column), 64 rows/block, 4-row unroll.
template<bool RELU, int K>
__global__ void gemm_kernel(const void* __restrict__ X, int x_flagged,
                            const void* __restrict__ W,
                            const void* __restrict__ b,
                            float* __restrict__ out, int n,
                            const int* __restrict__ dflag) {
    __shared__ float Wl[K * 128];
    int isb  = *dflag;
    int xisb = x_flagged ? isb : 0;
    int j = threadIdx.x;
    for (int idx = j; idx < K * 128; idx += 128)
        Wl[idx] = loadf(W, idx, isb);
    __syncthreads();
    float bj = loadf(b, j, isb);
    int row0 = blockIdx.x * 64;
    for (int i0 = 0; i0 < 64; i0 += 4) {
        int i = row0 + i0;
        if (i >= n) break;
        size_t r0 = (size_t)i * K;
        float a0 = bj, a1 = bj, a2 = bj, a3 = bj;
        for (int k = 0; k < K; ++k) {
            float w = Wl[k * 128 + j];
            float v0 = loadf(X, r0 + k, xisb);
            float v1 = loadf(X, r0 + K + k, xisb);
            float v2 = loadf(X, r0 + 2 * K + k, xisb);
            float v3 = loadf(X, r0 + 3 * K + k, xisb);
            if (RELU) {
                v0 = fmaxf(v0, 0.f); v1 = fmaxf(v1, 0.f);
                v2 = fmaxf(v2, 0.f); v3 = fmaxf(v3, 0.f);
            }
            a0 = fmaf(v0, w, a0);
            a1 = fmaf(v1, w, a1);
            a2 = fmaf(v2, w, a2);
            a3 = fmaf(v3, w, a3);
        }
        float* o = out + (size_t)i * 128 + j;
        o[0] = a0; o[128] = a1; o[256] = a2; o[384] = a3;
    }
}

// out[elem_off + row*d + j] = agg[row,j] / (||agg[row,:]|| + 1e-9); one wave/row.
// Store dtype follows *dflag (bf16 if inputs were bf16, else fp32).
__global__ void l2norm_kernel(const float* __restrict__ agg, int d,
                              void* __restrict__ out, size_t elem_off, int n,
                              const int* __restrict__ dflag) {
    int row = blockIdx.x * (blockDim.x >> 6) + (threadIdx.x >> 6);
    if (row >= n) return;
    int isb  = *dflag;
    int lane = threadIdx.x & 63;
    const float* a = agg + (size_t)row * d;
    float ss = 0.f;
    for (int j = lane; j < d; j += 64) { float x = a[j]; ss += x * x; }
    #pragma unroll
    for (int off = 32; off > 0; off >>= 1) ss += __shfl_down(ss, off);
    ss = __shfl(ss, 0);
    float inv = 1.0f / (sqrtf(ss) + 1e-9f);
    size_t b = elem_off + (size_t)row * d;
    if (isb) {
        bf16* o = (bf16*)out;
        for (int j = lane; j < d; j += 64) o[b + j] = __float2bfloat16(a[j] * inv);
    } else {
        float* o = (float*)out;
        for (int j = lane; j < d; j += 64) o[b + j] = a[j] * inv;
    }
}

static inline int spmm_grid(int nE) { return (nE + 3) / 4; }  // 4 edges / 256-thr block

extern "C" void kernel_launch(void* const* d_in, const int* in_sizes, int n_in,
                              void* d_out, int out_size, void* d_ws, size_t ws_size,
                              hipStream_t stream) {
    const void* f1   = d_in[0];
    const void* f2   = d_in[1];
    const void* f3   = d_in[2];
    const void* wemb = d_in[3];
    const int*  a11r = (const int*)d_in[4];
    const int*  a11c = (const int*)d_in[5];
    const void* a11v = d_in[6];
    const int*  a22r = (const int*)d_in[7];
    const int*  a22c = (const int*)d_in[8];
    const void* a22v = d_in[9];
    const int*  a33r = (const int*)d_in[10];
    const int*  a33c = (const int*)d_in[11];
    const void* a33v = d_in[12];
    const int*  a01r = (const int*)d_in[13];
    const int*  a01c = (const int*)d_in[14];
    const void* a01v = d_in[15];
    const int*  a02r = (const int*)d_in[16];
    const int*  a02c = (const int*)d_in[17];
    const void* a02v = d_in[18];
    const int*  a03r = (const int*)d_in[19];
    const int*  a03c = (const int*)d_in[20];
    const void* a03v = d_in[21];
    const void* W3   = d_in[22];
    const void* b3   = d_in[23];
    const void* W1_2 = d_in[24];
    const void* b1_2 = d_in[25];
    const void* W2_2 = d_in[26];
    const void* b2_2 = d_in[27];
    const void* W3_2 = d_in[28];
    const void* b3_2 = d_in[29];

    int*   dflag = (int*)d_ws;
    float* base  = (float*)d_ws + 16;       // buffers start 64 B in; flag survives
    float* S0   = base;                     // 20000*128
    float* S1   = base + 2560000;           // 20000*128
    float* AGG1 = S1;                       // 10000*128 (S1 dead when used)
    float* E0   = base;                     // 10000*128
    float* E1   = base + 1280000;           // 10000*128
    float* AGG2 = base + 1280000;           // 10000*428 (E1 dead when used)
    float* P3a  = base;                     // 60*128
    float* P3b  = base + 7680;              // 60*128
    float* AGG3 = base + 15360;             // 10000*128

    // Output element offsets (width flag-dependent, handled in l2norm):
    const size_t OUT1_OFF = 0;
    const size_t OUT2_OFF = (size_t)N_DOC * DD;                       // 1,280,000
    const size_t OUT3_OFF = OUT2_OFF + (size_t)N_DOC * (DD + D_WEMB); // 5,560,000

    dim3 blk(256);

    detect_kernel<<<1, 256, 0, stream>>>((const unsigned*)f1, dflag);

    // ---------------- type 1 (words) ----------------
    hipMemsetAsync(S0, 0, (size_t)N_WORD * DD * 4, stream);
    spmm_kernel<false><<<spmm_grid(E11), blk, 0, stream>>>(
        a11r, a11c, a11v, f1, DD, 1, S0, DD, 0, DD, E11, dflag);      // S0 = A11@f1
    gemm_kernel<true, 128><<<(N_WORD + 63) / 64, 128, 0, stream>>>(
        S0, 0, W1_2, b1_2, S1, N_WORD, dflag);                        // S1 = relu(S0)@W+b
    hipMemsetAsync(S0, 0, (size_t)N_WORD * DD * 4, stream);
    spmm_kernel<false><<<spmm_grid(E11), blk, 0, stream>>>(
        a11r, a11c, a11v, S1, DD, 0, S0, DD, 0, DD, E11, dflag);      // S0 = A11@S1
    hipMemsetAsync(AGG1, 0, (size_t)N_DOC * DD * 4, stream);
    spmm_kernel<true><<<spmm_grid(E01), blk, 0, stream>>>(
        a01r, a01c, a01v, S0, DD, 0, AGG1, DD, 0, DD, E01, dflag);    // AGG1 = A01@relu(S0)
    l2norm_kernel<<<(N_DOC + 3) / 4, blk, 0, stream>>>(
        AGG1, DD, d_out, OUT1_OFF, N_DOC, dflag);

    // ---------------- type 2 (entities) ----------------
    hipMemsetAsync(E0, 0, (size_t)N_ENT * DD * 4, stream);
    spmm_kernel<false><<<spmm_grid(E22), blk, 0, stream>>>(
        a22r, a22c, a22v, f2, DD, 1, E0, DD, 0, DD, E22, dflag);      // E0 = A22@f2
    gemm_kernel<true, 128><<<(N_ENT + 63) / 64, 128, 0, stream>>>(
        E0, 0, W2_2, b2_2, E1, N_ENT, dflag);                         // E1 = relu(E0)@W+b
    hipMemsetAsync(E0, 0, (size_t)N_ENT * DD * 4, stream);
    spmm_kernel<false><<<spmm_grid(E22), blk, 0, stream>>>(
        a22r, a22c, a22v, E1, DD, 0, E0, DD, 0, DD, E22, dflag);      // E0 = A22@E1
    hipMemsetAsync(AGG2, 0, (size_t)N_DOC * (DD + D_WEMB) * 4, stream);
    spmm_kernel<true><<<spmm_grid(E02), blk, 0, stream>>>(
        a02r, a02c, a02v, E0, DD, 0, AGG2, DD + D_WEMB, 0, DD, E02, dflag);
    spmm_kernel<false><<<spmm_grid(E02), blk, 0, stream>>>(
        a02r, a02c, a02v, wemb, D_WEMB, 1, AGG2, DD + D_WEMB, DD, D_WEMB, E02, dflag);
    l2norm_kernel<<<(N_DOC + 3) / 4, blk, 0, stream>>>(
        AGG2, DD + D_WEMB, d_out, OUT2_OFF, N_DOC, dflag);

    // ---------------- type 3 (POS) ----------------
    gemm_kernel<false, 60><<<1, 128, 0, stream>>>(f3, 1, W3, b3, P3a, N_POS, dflag);
    hipMemsetAsync(P3b, 0, (size_t)N_POS * DD * 4, stream);
    spmm_kernel<false><<<spmm_grid(E33), blk, 0, stream>>>(
        a33r, a33c, a33v, P3a, DD, 0, P3b, DD, 0, DD, E33, dflag);    // P3b = A33@P3a
    gemm_kernel<true, 128><<<1, 128, 0, stream>>>(
        P3b, 0, W3_2, b3_2, P3a, N_POS, dflag);                       // P3a = relu(P3b)@W+b
    hipMemsetAsync(P3b, 0, (size_t)N_POS * DD * 4, stream);
    spmm_kernel<false><<<spmm_grid(E33), blk, 0, stream>>>(
        a33r, a33c, a33v, P3a, DD, 0, P3b, DD, 0, DD, E33, dflag);    // P3b = A33@P3a
    hipMemsetAsync(AGG3, 0, (size_t)N_DOC * DD * 4, stream);
    spmm_kernel<true><<<spmm_grid(E03), blk, 0, stream>>>(
        a03r, a03c, a03v, P3b, DD, 0, AGG3, DD, 0, DD, E03, dflag);   // AGG3 = A03@relu(P3b)
    l2norm_kernel<<<(N_DOC + 3) / 4, blk, 0, stream>>>(
        AGG3, DD, d_out, OUT3_OFF, N_DOC, dflag);
}

// Round 5
// 2055.382 us; speedup vs baseline: 1.3273x; 1.3273x over previous
//
#include <hip/hip_runtime.h>
#include <hip/hip_bf16.h>

typedef __hip_bfloat16 bf16;

#define N_DOC   10000
#define N_WORD  20000
#define N_ENT   10000
#define N_POS   60
#define DD      128
#define D_WEMB  300
#define E11     320000
#define E22     160000
#define E33     3600
#define E01     300000
#define E02     100000
#define E03     150000

// Runtime dtype flag (ws[0]): 1 if float inputs are packed bf16, 0 if fp32.
__device__ __forceinline__ float loadf(const void* p, size_t i, int isb) {
    return isb ? __bfloat162float(((const bf16*)p)[i])
               : ((const float*)p)[i];
}
__device__ __forceinline__ float b2f(unsigned u16) {
    union { unsigned v; float f; } x; x.v = u16 << 16; return x.f;
}
__device__ __forceinline__ unsigned f2b(float f) {
    bf16 h = __float2bfloat16(f);
    union { bf16 h; unsigned short u; } x; x.h = h; return (unsigned)x.u;
}

// Detect input dtype from a randn fp32-or-bf16 buffer (see R2 notes).
__global__ void detect_kernel(const unsigned* __restrict__ probe, int* __restrict__ flag) {
    __shared__ int cnt;
    if (threadIdx.x == 0) cnt = 0;
    __syncthreads();
    int insane = 0;
    for (int i = threadIdx.x; i < 1024; i += 256) {
        float x = __uint_as_float(probe[i]);
        float a = fabsf(x);
        if (!(a > 1e-10f && a < 1e10f)) insane++;
    }
    atomicAdd(&cnt, insane);
    __syncthreads();
    if (threadIdx.x == 0) *flag = (cnt > 512) ? 1 : 0;
}

// dst[rows[e], doff+0..d) += vals[e] * act(src[cols[e], 0..d)); one wave/edge.
// 2 cols/lane: float2 / packed-bf16x2 loads (d always even; bases 2-elem aligned).
template<bool RELU>
__global__ void spmm_kernel(const int* __restrict__ rows, const int* __restrict__ cols,
                            const void* __restrict__ vals,
                            const void* __restrict__ src, int sstride, int src_flagged,
                            float* __restrict__ dst, int dstride, int doff,
                            int d, int nE, const int* __restrict__ dflag) {
    int e = blockIdx.x * (blockDim.x >> 6) + (threadIdx.x >> 6);
    if (e >= nE) return;
    int isb  = *dflag;
    int sisb = src_flagged ? isb : 0;
    int lane = threadIdx.x & 63;
    int r = rows[e];
    int c = cols[e];
    float v = loadf(vals, e, isb);
    size_t sbase = (size_t)c * sstride;
    float* dp = dst + (size_t)r * dstride + doff;
    if (sisb) {
        const unsigned* sp = (const unsigned*)((const bf16*)src + sbase);
        for (int j = 2 * lane; j < d; j += 128) {
            unsigned u = sp[j >> 1];
            float x0 = b2f(u & 0xffffu);
            float x1 = b2f(u >> 16);
            if (RELU) { x0 = fmaxf(x0, 0.f); x1 = fmaxf(x1, 0.f); }
            atomicAdd(dp + j,     v * x0);
            atomicAdd(dp + j + 1, v * x1);
        }
    } else {
        const float2* sp = (const float2*)((const float*)src + sbase);
        for (int j = 2 * lane; j < d; j += 128) {
            float2 x = sp[j >> 1];
            if (RELU) { x.x = fmaxf(x.x, 0.f); x.y = fmaxf(x.y, 0.f); }
            atomicAdd(dp + j,     v * x.x);
            atomicAdd(dp + j + 1, v * x.y);
        }
    }
}

// out[n x 128] = act(X[n x 128]) @ W[128 x 128] + b.  X fp32 (ws buffer).
// 256 threads: j = tid&127 (out column), h = tid>>7 (row half). 64 rows/block.
// W staged fp32 in 64 KB LDS (vectorized staging); X via wave-uniform float4
// loads (k-vectorized). W LDS reads: lanes j consecutive -> 2 lanes/bank = free.
template<bool RELU>
__global__ __launch_bounds__(256) void gemm128_kernel(
        const float* __restrict__ X, const void* __restrict__ W,
        const void* __restrict__ b, float* __restrict__ out, int n,
        const int* __restrict__ dflag) {
    __shared__ float Wl[128 * 128];
    int isb = *dflag;
    int tid = threadIdx.x;
    if (isb) {
        const uint2* Wg = (const uint2*)W;           // 4 bf16 per uint2
        float4* Wl4 = (float4*)Wl;
        for (int idx = tid; idx < 4096; idx += 256) {
            uint2 u = Wg[idx];
            float4 vv;
            vv.x = b2f(u.x & 0xffffu);
            vv.y = b2f(u.x >> 16);
            vv.z = b2f(u.y & 0xffffu);
            vv.w = b2f(u.y >> 16);
            Wl4[idx] = vv;
        }
    } else {
        const float4* Wg = (const float4*)W;
        float4* Wl4 = (float4*)Wl;
        for (int idx = tid; idx < 4096; idx += 256) Wl4[idx] = Wg[idx];
    }
    __syncthreads();
    int j = tid & 127;
    int h = tid >> 7;
    float bj = loadf(b, j, isb);
    int row0 = blockIdx.x * 64 + h * 32;
    for (int q = 0; q < 8; ++q) {
        int gi = row0 + q * 4;                        // n % 4 == 0 always here
        if (gi >= n) break;
        const float4* x0 = (const float4*)(X + (size_t)gi * 128);
        const float4* x1 = x0 + 32;
        const float4* x2 = x1 + 32;
        const float4* x3 = x2 + 32;
        float a0 = bj, a1 = bj, a2 = bj, a3 = bj;
        #pragma unroll 4
        for (int k4 = 0; k4 < 32; ++k4) {
            float4 v0 = x0[k4], v1 = x1[k4], v2 = x2[k4], v3 = x3[k4];
            if (RELU) {
                v0.x = fmaxf(v0.x, 0.f); v0.y = fmaxf(v0.y, 0.f); v0.z = fmaxf(v0.z, 0.f); v0.w = fmaxf(v0.w, 0.f);
                v1.x = fmaxf(v1.x, 0.f); v1.y = fmaxf(v1.y, 0.f); v1.z = fmaxf(v1.z, 0.f); v1.w = fmaxf(v1.w, 0.f);
                v2.x = fmaxf(v2.x, 0.f); v2.y = fmaxf(v2.y, 0.f); v2.z = fmaxf(v2.z, 0.f); v2.w = fmaxf(v2.w, 0.f);
                v3.x = fmaxf(v3.x, 0.f); v3.y = fmaxf(v3.y, 0.f); v3.z = fmaxf(v3.z, 0.f); v3.w = fmaxf(v3.w, 0.f);
            }
            float w0 = Wl[(4 * k4 + 0) * 128 + j];
            float w1 = Wl[(4 * k4 + 1) * 128 + j];
            float w2 = Wl[(4 * k4 + 2) * 128 + j];
            float w3 = Wl[(4 * k4 + 3) * 128 + j];
            a0 = fmaf(v0.w, w3, fmaf(v0.z, w2, fmaf(v0.y, w1, fmaf(v0.x, w0, a0))));
            a1 = fmaf(v1.w, w3, fmaf(v1.z, w2, fmaf(v1.y, w1, fmaf(v1.x, w0, a1))));
            a2 = fmaf(v2.w, w3, fmaf(v2.z, w2, fmaf(v2.y, w1, fmaf(v2.x, w0, a2))));
            a3 = fmaf(v3.w, w3, fmaf(v3.z, w2, fmaf(v3.y, w1, fmaf(v3.x, w0, a3))));
        }
        float* o = out + (size_t)gi * 128 + j;
        o[0] = a0; o[128] = a1; o[256] = a2; o[384] = a3;
    }
}

// Generic small GEMM (kept for the tiny K=60 type-3 first layer, grid=1).
template<bool RELU, int K>
__global__ void gemm_kernel(const void* __restrict__ X, int x_flagged,
                            const void* __restrict__ W,
                            const void* __restrict__ b,
                            float* __restrict__ out, int n,
                            const int* __restrict__ dflag) {
    __shared__ float Wl[K * 128];
    int isb  = *dflag;
    int xisb = x_flagged ? isb : 0;
    int j = threadIdx.x;
    for (int idx = j; idx < K * 128; idx += 128)
        Wl[idx] = loadf(W, idx, isb);
    __syncthreads();
    float bj = loadf(b, j, isb);
    int row0 = blockIdx.x * 64;
    for (int i0 = 0; i0 < 64; i0 += 4) {
        int i = row0 + i0;
        if (i >= n) break;
        size_t r0 = (size_t)i * K;
        float a0 = bj, a1 = bj, a2 = bj, a3 = bj;
        for (int k = 0; k < K; ++k) {
            float w = Wl[k * 128 + j];
            float v0 = loadf(X, r0 + k, xisb);
            float v1 = loadf(X, r0 + K + k, xisb);
            float v2 = loadf(X, r0 + 2 * K + k, xisb);
            float v3 = loadf(X, r0 + 3 * K + k, xisb);
            if (RELU) {
                v0 = fmaxf(v0, 0.f); v1 = fmaxf(v1, 0.f);
                v2 = fmaxf(v2, 0.f); v3 = fmaxf(v3, 0.f);
            }
            a0 = fmaf(v0, w, a0);
            a1 = fmaf(v1, w, a1);
            a2 = fmaf(v2, w, a2);
            a3 = fmaf(v3, w, a3);
        }
        float* o = out + (size_t)i * 128 + j;
        o[0] = a0; o[128] = a1; o[256] = a2; o[384] = a3;
    }
}

// out[elem_off + row*d + j] = agg[row,j] / (||agg[row,:]|| + 1e-9); one wave/row.
// float2 loads; packed bf162 (or float2) stores. d even; all bases 2-elem aligned.
__global__ void l2norm_kernel(const float* __restrict__ agg, int d,
                              void* __restrict__ out, size_t elem_off, int n,
                              const int* __restrict__ dflag) {
    int row = blockIdx.x * (blockDim.x >> 6) + (threadIdx.x >> 6);
    if (row >= n) return;
    int isb  = *dflag;
    int lane = threadIdx.x & 63;
    const float2* a2 = (const float2*)(agg + (size_t)row * d);
    float ss = 0.f;
    for (int j = 2 * lane; j < d; j += 128) {
        float2 x = a2[j >> 1];
        ss += x.x * x.x + x.y * x.y;
    }
    #pragma unroll
    for (int off = 32; off > 0; off >>= 1) ss += __shfl_down(ss, off);
    ss = __shfl(ss, 0);
    float inv = 1.0f / (sqrtf(ss) + 1e-9f);
    size_t bbase = elem_off + (size_t)row * d;
    if (isb) {
        unsigned* o = (unsigned*)((bf16*)out + bbase);
        for (int j = 2 * lane; j < d; j += 128) {
            float2 x = a2[j >> 1];
            o[j >> 1] = f2b(x.x * inv) | (f2b(x.y * inv) << 16);
        }
    } else {
        float2* o = (float2*)((float*)out + bbase);
        for (int j = 2 * lane; j < d; j += 128) {
            float2 x = a2[j >> 1];
            o[j >> 1] = make_float2(x.x * inv, x.y * inv);
        }
    }
}

static inline int spmm_grid(int nE) { return (nE + 3) / 4; }  // 4 edges / 256-thr block

extern "C" void kernel_launch(void* const* d_in, const int* in_sizes, int n_in,
                              void* d_out, int out_size, void* d_ws, size_t ws_size,
                              hipStream_t stream) {
    const void* f1   = d_in[0];
    const void* f2   = d_in[1];
    const void* f3   = d_in[2];
    const void* wemb = d_in[3];
    const int*  a11r = (const int*)d_in[4];
    const int*  a11c = (const int*)d_in[5];
    const void* a11v = d_in[6];
    const int*  a22r = (const int*)d_in[7];
    const int*  a22c = (const int*)d_in[8];
    const void* a22v = d_in[9];
    const int*  a33r = (const int*)d_in[10];
    const int*  a33c = (const int*)d_in[11];
    const void* a33v = d_in[12];
    const int*  a01r = (const int*)d_in[13];
    const int*  a01c = (const int*)d_in[14];
    const void* a01v = d_in[15];
    const int*  a02r = (const int*)d_in[16];
    const int*  a02c = (const int*)d_in[17];
    const void* a02v = d_in[18];
    const int*  a03r = (const int*)d_in[19];
    const int*  a03c = (const int*)d_in[20];
    const void* a03v = d_in[21];
    const void* W3   = d_in[22];
    const void* b3   = d_in[23];
    const void* W1_2 = d_in[24];
    const void* b1_2 = d_in[25];
    const void* W2_2 = d_in[26];
    const void* b2_2 = d_in[27];
    const void* W3_2 = d_in[28];
    const void* b3_2 = d_in[29];

    int*   dflag = (int*)d_ws;
    float* base  = (float*)d_ws + 16;       // buffers start 64 B in; flag survives
    float* S0   = base;                     // 20000*128
    float* S1   = base + 2560000;           // 20000*128
    float* AGG1 = S1;                       // 10000*128 (S1 dead when used)
    float* E0   = base;                     // 10000*128
    float* E1   = base + 1280000;           // 10000*128
    float* AGG2 = base + 1280000;           // 10000*428 (E1 dead when used)
    float* P3a  = base;                     // 60*128
    float* P3b  = base + 7680;              // 60*128
    float* AGG3 = base + 15360;             // 10000*128

    const size_t OUT1_OFF = 0;
    const size_t OUT2_OFF = (size_t)N_DOC * DD;                       // 1,280,000
    const size_t OUT3_OFF = OUT2_OFF + (size_t)N_DOC * (DD + D_WEMB); // 5,560,000

    dim3 blk(256);

    detect_kernel<<<1, 256, 0, stream>>>((const unsigned*)f1, dflag);

    // ---------------- type 1 (words) ----------------
    hipMemsetAsync(S0, 0, (size_t)N_WORD * DD * 4, stream);
    spmm_kernel<false><<<spmm_grid(E11), blk, 0, stream>>>(
        a11r, a11c, a11v, f1, DD, 1, S0, DD, 0, DD, E11, dflag);      // S0 = A11@f1
    gemm128_kernel<true><<<(N_WORD + 63) / 64, 256, 0, stream>>>(
        S0, W1_2, b1_2, S1, N_WORD, dflag);                           // S1 = relu(S0)@W+b
    hipMemsetAsync(S0, 0, (size_t)N_WORD * DD * 4, stream);
    spmm_kernel<false><<<spmm_grid(E11), blk, 0, stream>>>(
        a11r, a11c, a11v, S1, DD, 0, S0, DD, 0, DD, E11, dflag);      // S0 = A11@S1
    hipMemsetAsync(AGG1, 0, (size_t)N_DOC * DD * 4, stream);
    spmm_kernel<true><<<spmm_grid(E01), blk, 0, stream>>>(
        a01r, a01c, a01v, S0, DD, 0, AGG1, DD, 0, DD, E01, dflag);    // AGG1 = A01@relu(S0)
    l2norm_kernel<<<(N_DOC + 3) / 4, blk, 0, stream>>>(
        AGG1, DD, d_out, OUT1_OFF, N_DOC, dflag);

    // ---------------- type 2 (entities) ----------------
    hipMemsetAsync(E0, 0, (size_t)N_ENT * DD * 4, stream);
    spmm_kernel<false><<<spmm_grid(E22), blk, 0, stream>>>(
        a22r, a22c, a22v, f2, DD, 1, E0, DD, 0, DD, E22, dflag);      // E0 = A22@f2
    gemm128_kernel<true><<<(N_ENT + 63) / 64, 256, 0, stream>>>(
        E0, W2_2, b2_2, E1, N_ENT, dflag);                            // E1 = relu(E0)@W+b
    hipMemsetAsync(E0, 0, (size_t)N_ENT * DD * 4, stream);
    spmm_kernel<false><<<spmm_grid(E22), blk, 0, stream>>>(
        a22r, a22c, a22v, E1, DD, 0, E0, DD, 0, DD, E22, dflag);      // E0 = A22@E1
    hipMemsetAsync(AGG2, 0, (size_t)N_DOC * (DD + D_WEMB) * 4, stream);
    spmm_kernel<true><<<spmm_grid(E02), blk, 0, stream>>>(
        a02r, a02c, a02v, E0, DD, 0, AGG2, DD + D_WEMB, 0, DD, E02, dflag);
    spmm_kernel<false><<<spmm_grid(E02), blk, 0, stream>>>(
        a02r, a02c, a02v, wemb, D_WEMB, 1, AGG2, DD + D_WEMB, DD, D_WEMB, E02, dflag);
    l2norm_kernel<<<(N_DOC + 3) / 4, blk, 0, stream>>>(
        AGG2, DD + D_WEMB, d_out, OUT2_OFF, N_DOC, dflag);

    // ---------------- type 3 (POS) ----------------
    gemm_kernel<false, 60><<<1, 128, 0, stream>>>(f3, 1, W3, b3, P3a, N_POS, dflag);
    hipMemsetAsync(P3b, 0, (size_t)N_POS * DD * 4, stream);
    spmm_kernel<false><<<spmm_grid(E33), blk, 0, stream>>>(
        a33r, a33c, a33v, P3a, DD, 0, P3b, DD, 0, DD, E33, dflag);    // P3b = A33@P3a
    gemm128_kernel<true><<<1, 256, 0, stream>>>(
        P3b, W3_2, b3_2, P3a, N_POS, dflag);                          // P3a = relu(P3b)@W+b
    hipMemsetAsync(P3b, 0, (size_t)N_POS * DD * 4, stream);
    spmm_kernel<false><<<spmm_grid(E33), blk, 0, stream>>>(
        a33r, a33c, a33v, P3a, DD, 0, P3b, DD, 0, DD, E33, dflag);    // P3b = A33@P3a
    hipMemsetAsync(AGG3, 0, (size_t)N_DOC * DD * 4, stream);
    spmm_kernel<true><<<spmm_grid(E03), blk, 0, stream>>>(
        a03r, a03c, a03v, P3b, DD, 0, AGG3, DD, 0, DD, E03, dflag);   // AGG3 = A03@relu(P3b)
    l2norm_kernel<<<(N_DOC + 3) / 4, blk, 0, stream>>>(
        AGG3, DD, d_out, OUT3_OFF, N_DOC, dflag);
}

// Round 6
// 1064.319 us; speedup vs baseline: 2.5633x; 1.9312x over previous
//
#include <hip/hip_runtime.h>
#include <hip/hip_bf16.h>

typedef __hip_bfloat16 bf16;

#define N_DOC   10000
#define N_WORD  20000
#define N_ENT   10000
#define N_POS   60
#define DD      128
#define D_WEMB  300
#define E11     320000
#define E22     160000
#define E33     3600
#define E01     300000
#define E02     100000
#define E03     150000

// Runtime dtype flag (ws[0]): 1 if float inputs are packed bf16, 0 if fp32.
__device__ __forceinline__ float loadf(const void* p, size_t i, int isb) {
    return isb ? __bfloat162float(((const bf16*)p)[i])
               : ((const float*)p)[i];
}
__device__ __forceinline__ float b2f(unsigned u16) {
    union { unsigned v; float f; } x; x.v = u16 << 16; return x.f;
}
__device__ __forceinline__ unsigned f2b(float f) {
    bf16 h = __float2bfloat16(f);
    union { bf16 h; unsigned short u; } x; x.h = h; return (unsigned)x.u;
}

// Detect input dtype from a randn fp32-or-bf16 buffer (see R2 notes).
__global__ void detect_kernel(const unsigned* __restrict__ probe, int* __restrict__ flag) {
    __shared__ int cnt;
    if (threadIdx.x == 0) cnt = 0;
    __syncthreads();
    int insane = 0;
    for (int i = threadIdx.x; i < 1024; i += 256) {
        float x = __uint_as_float(probe[i]);
        float a = fabsf(x);
        if (!(a > 1e-10f && a < 1e10f)) insane++;
    }
    atomicAdd(&cnt, insane);
    __syncthreads();
    if (threadIdx.x == 0) *flag = (cnt > 512) ? 1 : 0;
}

// ======================= CSR build =======================
__global__ void hist_kernel(const int* __restrict__ rows, int nE, int* __restrict__ cnt) {
    int i = blockIdx.x * blockDim.x + threadIdx.x;
    if (i < nE) atomicAdd(cnt + rows[i], 1);
}

// Exclusive scan of cnt[0..n) into rp[0..n]; single block of 1024 threads.
__global__ __launch_bounds__(1024) void scan_kernel(const int* __restrict__ cnt,
                                                    int* __restrict__ rp, int n) {
    __shared__ int buf[1024];
    __shared__ int carry;
    int t = threadIdx.x;
    if (t == 0) carry = 0;
    __syncthreads();
    for (int base = 0; base < n; base += 1024) {
        int x = (base + t < n) ? cnt[base + t] : 0;
        buf[t] = x;
        __syncthreads();
        for (int off = 1; off < 1024; off <<= 1) {
            int y = (t >= off) ? buf[t - off] : 0;
            __syncthreads();
            buf[t] += y;
            __syncthreads();
        }
        if (base + t < n) rp[base + t] = carry + buf[t] - x;
        __syncthreads();
        if (t == 0) carry += buf[1023];
        __syncthreads();
    }
    if (t == 0) rp[n] = carry;
}

__global__ void copy_kernel(const int* __restrict__ src, int* __restrict__ dst, int n) {
    int i = blockIdx.x * blockDim.x + threadIdx.x;
    if (i < n) dst[i] = src[i];
}

// pairs[p] = (col, val_fp32_bits), p allocated from cursor[row].
__global__ void scatter_kernel(const int* __restrict__ rows, const int* __restrict__ cols,
                               const void* __restrict__ vals,
                               int* __restrict__ cursor, int2* __restrict__ pairs,
                               int nE, const int* __restrict__ dflag) {
    int i = blockIdx.x * blockDim.x + threadIdx.x;
    if (i >= nE) return;
    int r = rows[i];
    int p = atomicAdd(cursor + r, 1);
    float v = loadf(vals, i, *dflag);
    pairs[p] = make_int2(cols[i], __float_as_int(v));
}

// ======================= gather SpMM (no atomics) =======================
// dst[row, doff+0..D) = sum_e vals[e] * act(src[cols[e], 0..D)); one wave/row.
// Row accumulated in registers (float2 slots), written once.
template<bool RELU, int D>
__global__ void spmm_gather(const int* __restrict__ rowptr, const int2* __restrict__ pairs,
                            const void* __restrict__ src, int sstride, int src_flagged,
                            float* __restrict__ dst, int dstride, int doff,
                            int n, const int* __restrict__ dflag) {
    constexpr int PAIRS = D / 2;
    constexpr int NS = (PAIRS + 63) / 64;
    int row = blockIdx.x * (blockDim.x >> 6) + (threadIdx.x >> 6);
    if (row >= n) return;
    int isb  = *dflag;
    int sisb = src_flagged ? isb : 0;
    int lane = threadIdx.x & 63;
    int e0 = rowptr[row], e1 = rowptr[row + 1];
    float2 acc[NS];
    #pragma unroll
    for (int s = 0; s < NS; ++s) acc[s] = make_float2(0.f, 0.f);
    if (sisb) {
        for (int e = e0; e < e1; ++e) {
            int2 p = pairs[e];
            float v = __int_as_float(p.y);
            const unsigned* sp = (const unsigned*)((const bf16*)src + (size_t)p.x * sstride);
            #pragma unroll
            for (int s = 0; s < NS; ++s) {
                int pi = lane + 64 * s;
                if (pi < PAIRS) {
                    unsigned u = sp[pi];
                    float x0 = b2f(u & 0xffffu), x1 = b2f(u >> 16);
                    if (RELU) { x0 = fmaxf(x0, 0.f); x1 = fmaxf(x1, 0.f); }
                    acc[s].x = fmaf(v, x0, acc[s].x);
                    acc[s].y = fmaf(v, x1, acc[s].y);
                }
            }
        }
    } else {
        for (int e = e0; e < e1; ++e) {
            int2 p = pairs[e];
            float v = __int_as_float(p.y);
            const float2* sp = (const float2*)((const float*)src + (size_t)p.x * sstride);
            #pragma unroll
            for (int s = 0; s < NS; ++s) {
                int pi = lane + 64 * s;
                if (pi < PAIRS) {
                    float2 x = sp[pi];
                    if (RELU) { x.x = fmaxf(x.x, 0.f); x.y = fmaxf(x.y, 0.f); }
                    acc[s].x = fmaf(v, x.x, acc[s].x);
                    acc[s].y = fmaf(v, x.y, acc[s].y);
                }
            }
        }
    }
    float2* dp = (float2*)(dst + (size_t)row * dstride + doff);   // 8B-aligned (even elem idx)
    #pragma unroll
    for (int s = 0; s < NS; ++s) {
        int pi = lane + 64 * s;
        if (pi < PAIRS) dp[pi] = acc[s];
    }
}

// ======================= atomic SpMM (ws_size fallback) =======================
template<bool RELU>
__global__ void spmm_kernel(const int* __restrict__ rows, const int* __restrict__ cols,
                            const void* __restrict__ vals,
                            const void* __restrict__ src, int sstride, int src_flagged,
                            float* __restrict__ dst, int dstride, int doff,
                            int d, int nE, const int* __restrict__ dflag) {
    int e = blockIdx.x * (blockDim.x >> 6) + (threadIdx.x >> 6);
    if (e >= nE) return;
    int isb  = *dflag;
    int sisb = src_flagged ? isb : 0;
    int lane = threadIdx.x & 63;
    int r = rows[e];
    int c = cols[e];
    float v = loadf(vals, e, isb);
    size_t sbase = (size_t)c * sstride;
    float* dp = dst + (size_t)r * dstride + doff;
    if (sisb) {
        const unsigned* sp = (const unsigned*)((const bf16*)src + sbase);
        for (int j = 2 * lane; j < d; j += 128) {
            unsigned u = sp[j >> 1];
            float x0 = b2f(u & 0xffffu);
            float x1 = b2f(u >> 16);
            if (RELU) { x0 = fmaxf(x0, 0.f); x1 = fmaxf(x1, 0.f); }
            atomicAdd(dp + j,     v * x0);
            atomicAdd(dp + j + 1, v * x1);
        }
    } else {
        const float2* sp = (const float2*)((const float*)src + sbase);
        for (int j = 2 * lane; j < d; j += 128) {
            float2 x = sp[j >> 1];
            if (RELU) { x.x = fmaxf(x.x, 0.f); x.y = fmaxf(x.y, 0.f); }
            atomicAdd(dp + j,     v * x.x);
            atomicAdd(dp + j + 1, v * x.y);
        }
    }
}

// ======================= dense GEMMs =======================
// out[n x 128] = act(X[n x 128]) @ W[128 x 128] + b.  X fp32 (ws buffer).
template<bool RELU>
__global__ __launch_bounds__(256) void gemm128_kernel(
        const float* __restrict__ X, const void* __restrict__ W,
        const void* __restrict__ b, float* __restrict__ out, int n,
        const int* __restrict__ dflag) {
    __shared__ float Wl[128 * 128];
    int isb = *dflag;
    int tid = threadIdx.x;
    if (isb) {
        const uint2* Wg = (const uint2*)W;
        float4* Wl4 = (float4*)Wl;
        for (int idx = tid; idx < 4096; idx += 256) {
            uint2 u = Wg[idx];
            float4 vv;
            vv.x = b2f(u.x & 0xffffu);
            vv.y = b2f(u.x >> 16);
            vv.z = b2f(u.y & 0xffffu);
            vv.w = b2f(u.y >> 16);
            Wl4[idx] = vv;
        }
    } else {
        const float4* Wg = (const float4*)W;
        float4* Wl4 = (float4*)Wl;
        for (int idx = tid; idx < 4096; idx += 256) Wl4[idx] = Wg[idx];
    }
    __syncthreads();
    int j = tid & 127;
    int h = tid >> 7;
    float bj = loadf(b, j, isb);
    int row0 = blockIdx.x * 64 + h * 32;
    for (int q = 0; q < 8; ++q) {
        int gi = row0 + q * 4;
        if (gi >= n) break;
        const float4* x0 = (const float4*)(X + (size_t)gi * 128);
        const float4* x1 = x0 + 32;
        const float4* x2 = x1 + 32;
        const float4* x3 = x2 + 32;
        float a0 = bj, a1 = bj, a2 = bj, a3 = bj;
        #pragma unroll 4
        for (int k4 = 0; k4 < 32; ++k4) {
            float4 v0 = x0[k4], v1 = x1[k4], v2 = x2[k4], v3 = x3[k4];
            if (RELU) {
                v0.x = fmaxf(v0.x, 0.f); v0.y = fmaxf(v0.y, 0.f); v0.z = fmaxf(v0.z, 0.f); v0.w = fmaxf(v0.w, 0.f);
                v1.x = fmaxf(v1.x, 0.f); v1.y = fmaxf(v1.y, 0.f); v1.z = fmaxf(v1.z, 0.f); v1.w = fmaxf(v1.w, 0.f);
                v2.x = fmaxf(v2.x, 0.f); v2.y = fmaxf(v2.y, 0.f); v2.z = fmaxf(v2.z, 0.f); v2.w = fmaxf(v2.w, 0.f);
                v3.x = fmaxf(v3.x, 0.f); v3.y = fmaxf(v3.y, 0.f); v3.z = fmaxf(v3.z, 0.f); v3.w = fmaxf(v3.w, 0.f);
            }
            float w0 = Wl[(4 * k4 + 0) * 128 + j];
            float w1 = Wl[(4 * k4 + 1) * 128 + j];
            float w2 = Wl[(4 * k4 + 2) * 128 + j];
            float w3 = Wl[(4 * k4 + 3) * 128 + j];
            a0 = fmaf(v0.w, w3, fmaf(v0.z, w2, fmaf(v0.y, w1, fmaf(v0.x, w0, a0))));
            a1 = fmaf(v1.w, w3, fmaf(v1.z, w2, fmaf(v1.y, w1, fmaf(v1.x, w0, a1))));
            a2 = fmaf(v2.w, w3, fmaf(v2.z, w2, fmaf(v2.y, w1, fmaf(v2.x, w0, a2))));
            a3 = fmaf(v3.w, w3, fmaf(v3.z, w2, fmaf(v3.y, w1, fmaf(v3.x, w0, a3))));
        }
        float* o = out + (size_t)gi * 128 + j;
        o[0] = a0; o[128] = a1; o[256] = a2; o[384] = a3;
    }
}

// Generic small GEMM (tiny K=60 type-3 first layer, grid=1).
template<bool RELU, int K>
__global__ void gemm_kernel(const void* __restrict__ X, int x_flagged,
                            const void* __restrict__ W,
                            const void* __restrict__ b,
                            float* __restrict__ out, int n,
                            const int* __restrict__ dflag) {
    __shared__ float Wl[K * 128];
    int isb  = *dflag;
    int xisb = x_flagged ? isb : 0;
    int j = threadIdx.x;
    for (int idx = j; idx < K * 128; idx += 128)
        Wl[idx] = loadf(W, idx, isb);
    __syncthreads();
    float bj = loadf(b, j, isb);
    int row0 = blockIdx.x * 64;
    for (int i0 = 0; i0 < 64; i0 += 4) {
        int i = row0 + i0;
        if (i >= n) break;
        size_t r0 = (size_t)i * K;
        float a0 = bj, a1 = bj, a2 = bj, a3 = bj;
        for (int k = 0; k < K; ++k) {
            float w = Wl[k * 128 + j];
            float v0 = loadf(X, r0 + k, xisb);
            float v1 = loadf(X, r0 + K + k, xisb);
            float v2 = loadf(X, r0 + 2 * K + k, xisb);
            float v3 = loadf(X, r0 + 3 * K + k, xisb);
            if (RELU) {
                v0 = fmaxf(v0, 0.f); v1 = fmaxf(v1, 0.f);
                v2 = fmaxf(v2, 0.f); v3 = fmaxf(v3, 0.f);
            }
            a0 = fmaf(v0, w, a0);
            a1 = fmaf(v1, w, a1);
            a2 = fmaf(v2, w, a2);
            a3 = fmaf(v3, w, a3);
        }
        float* o = out + (size_t)i * 128 + j;
        o[0] = a0; o[128] = a1; o[256] = a2; o[384] = a3;
    }
}

// out[elem_off + row*d + j] = agg[row,j] / (||agg[row,:]|| + 1e-9); one wave/row.
__global__ void l2norm_kernel(const float* __restrict__ agg, int d,
                              void* __restrict__ out, size_t elem_off, int n,
                              const int* __restrict__ dflag) {
    int row = blockIdx.x * (blockDim.x >> 6) + (threadIdx.x >> 6);
    if (row >= n) return;
    int isb  = *dflag;
    int lane = threadIdx.x & 63;
    const float2* a2 = (const float2*)(agg + (size_t)row * d);
    float ss = 0.f;
    for (int j = 2 * lane; j < d; j += 128) {
        float2 x = a2[j >> 1];
        ss += x.x * x.x + x.y * x.y;
    }
    #pragma unroll
    for (int off = 32; off > 0; off >>= 1) ss += __shfl_down(ss, off);
    ss = __shfl(ss, 0);
    float inv = 1.0f / (sqrtf(ss) + 1e-9f);
    size_t bbase = elem_off + (size_t)row * d;
    if (isb) {
        unsigned* o = (unsigned*)((bf16*)out + bbase);
        for (int j = 2 * lane; j < d; j += 128) {
            float2 x = a2[j >> 1];
            o[j >> 1] = f2b(x.x * inv) | (f2b(x.y * inv) << 16);
        }
    } else {
        float2* o = (float2*)((float*)out + bbase);
        for (int j = 2 * lane; j < d; j += 128) {
            float2 x = a2[j >> 1];
            o[j >> 1] = make_float2(x.x * inv, x.y * inv);
        }
    }
}

static inline int spmm_grid(int nE) { return (nE + 3) / 4; }
static inline int row_grid(int n)   { return (n + 3) / 4; }

// Host helper: build CSR (rowptr rp[n+1], pairs) from COO on stream.
static void build_csr(hipStream_t stream, const int* rows, const int* cols,
                      const void* vals, int n, int nE,
                      int* rp, int* cur, int2* pairs, const int* dflag) {
    hipMemsetAsync(cur, 0, (size_t)n * 4, stream);
    hist_kernel<<<(nE + 255) / 256, 256, 0, stream>>>(rows, nE, cur);
    scan_kernel<<<1, 1024, 0, stream>>>(cur, rp, n);
    copy_kernel<<<(n + 255) / 256, 256, 0, stream>>>(rp, cur, n);
    scatter_kernel<<<(nE + 255) / 256, 256, 0, stream>>>(rows, cols, vals, cur, pairs, nE, dflag);
}

extern "C" void kernel_launch(void* const* d_in, const int* in_sizes, int n_in,
                              void* d_out, int out_size, void* d_ws, size_t ws_size,
                              hipStream_t stream) {
    const void* f1   = d_in[0];
    const void* f2   = d_in[1];
    const void* f3   = d_in[2];
    const void* wemb = d_in[3];
    const int*  a11r = (const int*)d_in[4];
    const int*  a11c = (const int*)d_in[5];
    const void* a11v = d_in[6];
    const int*  a22r = (const int*)d_in[7];
    const int*  a22c = (const int*)d_in[8];
    const void* a22v = d_in[9];
    const int*  a33r = (const int*)d_in[10];
    const int*  a33c = (const int*)d_in[11];
    const void* a33v = d_in[12];
    const int*  a01r = (const int*)d_in[13];
    const int*  a01c = (const int*)d_in[14];
    const void* a01v = d_in[15];
    const int*  a02r = (const int*)d_in[16];
    const int*  a02c = (const int*)d_in[17];
    const void* a02v = d_in[18];
    const int*  a03r = (const int*)d_in[19];
    const int*  a03c = (const int*)d_in[20];
    const void* a03v = d_in[21];
    const void* W3   = d_in[22];
    const void* b3   = d_in[23];
    const void* W1_2 = d_in[24];
    const void* b1_2 = d_in[25];
    const void* W2_2 = d_in[26];
    const void* b2_2 = d_in[27];
    const void* W3_2 = d_in[28];
    const void* b3_2 = d_in[29];

    int*   dflag = (int*)d_ws;
    float* base  = (float*)d_ws + 16;       // dense buffers start 64 B in
    float* S0   = base;                     // 20000*128
    float* S1   = base + 2560000;           // 20000*128
    float* AGG1 = S1;                       // 10000*128 (S1 dead when used)
    float* E0   = base;                     // 10000*128
    float* E1   = base + 1280000;           // 10000*128
    float* AGG2 = base + 1280000;           // 10000*428 (E1 dead when used)
    float* P3a  = base;                     // 60*128
    float* P3b  = base + 7680;              // 60*128
    float* AGG3 = base + 15360;             // 10000*128

    // CSR region after dense peak (base + 5,560,000 floats):
    int*  rp1    = (int*)(base + 5560000);  // up to 20001 (+1 pad)
    int*  cur1   = rp1 + 20002;             // up to 20000
    int*  rp2    = cur1 + 20000;            // up to 10001 (+1 pad)
    int*  cur2   = rp2 + 10002;             // up to 10000
    int2* pairs1 = (int2*)(cur2 + 10000);   // up to 320000 pairs (8B-aligned: checked)
    int2* pairs2 = pairs1 + 320000;         // up to 300000 pairs
    const size_t WS_NEEDED = 64 + (5560000ull + 60004ull + 2ull * 620000ull) * 4ull; // ~27.5 MB

    const size_t OUT1_OFF = 0;
    const size_t OUT2_OFF = (size_t)N_DOC * DD;                       // 1,280,000
    const size_t OUT3_OFF = OUT2_OFF + (size_t)N_DOC * (DD + D_WEMB); // 5,560,000

    dim3 blk(256);
    detect_kernel<<<1, 256, 0, stream>>>((const unsigned*)f1, dflag);

    if (ws_size >= WS_NEEDED) {
        // ================= CSR gather path (no atomics in spmm) =================
        // ---------------- type 1 (words) ----------------
        build_csr(stream, a11r, a11c, a11v, N_WORD, E11, rp1, cur1, pairs1, dflag);
        build_csr(stream, a01r, a01c, a01v, N_DOC,  E01, rp2, cur2, pairs2, dflag);
        spmm_gather<false, 128><<<row_grid(N_WORD), blk, 0, stream>>>(
            rp1, pairs1, f1, DD, 1, S0, DD, 0, N_WORD, dflag);        // S0 = A11@f1
        gemm128_kernel<true><<<(N_WORD + 63) / 64, 256, 0, stream>>>(
            S0, W1_2, b1_2, S1, N_WORD, dflag);                       // S1 = relu(S0)@W+b
        spmm_gather<false, 128><<<row_grid(N_WORD), blk, 0, stream>>>(
            rp1, pairs1, S1, DD, 0, S0, DD, 0, N_WORD, dflag);        // S0 = A11@S1
        spmm_gather<true, 128><<<row_grid(N_DOC), blk, 0, stream>>>(
            rp2, pairs2, S0, DD, 0, AGG1, DD, 0, N_DOC, dflag);       // AGG1 = A01@relu(S0)
        l2norm_kernel<<<row_grid(N_DOC), blk, 0, stream>>>(
            AGG1, DD, d_out, OUT1_OFF, N_DOC, dflag);

        // ---------------- type 2 (entities) ----------------
        build_csr(stream, a22r, a22c, a22v, N_ENT, E22, rp1, cur1, pairs1, dflag);
        build_csr(stream, a02r, a02c, a02v, N_DOC, E02, rp2, cur2, pairs2, dflag);
        spmm_gather<false, 128><<<row_grid(N_ENT), blk, 0, stream>>>(
            rp1, pairs1, f2, DD, 1, E0, DD, 0, N_ENT, dflag);         // E0 = A22@f2
        gemm128_kernel<true><<<(N_ENT + 63) / 64, 256, 0, stream>>>(
            E0, W2_2, b2_2, E1, N_ENT, dflag);                        // E1 = relu(E0)@W+b
        spmm_gather<false, 128><<<row_grid(N_ENT), blk, 0, stream>>>(
            rp1, pairs1, E1, DD, 0, E0, DD, 0, N_ENT, dflag);         // E0 = A22@E1
        spmm_gather<true, 128><<<row_grid(N_DOC), blk, 0, stream>>>(
            rp2, pairs2, E0, DD, 0, AGG2, DD + D_WEMB, 0, N_DOC, dflag);
        spmm_gather<false, 300><<<row_grid(N_DOC), blk, 0, stream>>>(
            rp2, pairs2, wemb, D_WEMB, 1, AGG2, DD + D_WEMB, DD, N_DOC, dflag);
        l2norm_kernel<<<row_grid(N_DOC), blk, 0, stream>>>(
            AGG2, DD + D_WEMB, d_out, OUT2_OFF, N_DOC, dflag);

        // ---------------- type 3 (POS) ----------------
        build_csr(stream, a33r, a33c, a33v, N_POS, E33, rp1, cur1, pairs1, dflag);
        build_csr(stream, a03r, a03c, a03v, N_DOC, E03, rp2, cur2, pairs2, dflag);
        gemm_kernel<false, 60><<<1, 128, 0, stream>>>(f3, 1, W3, b3, P3a, N_POS, dflag);
        spmm_gather<false, 128><<<row_grid(N_POS), blk, 0, stream>>>(
            rp1, pairs1, P3a, DD, 0, P3b, DD, 0, N_POS, dflag);       // P3b = A33@P3a
        gemm128_kernel<true><<<1, 256, 0, stream>>>(
            P3b, W3_2, b3_2, P3a, N_POS, dflag);                      // P3a = relu(P3b)@W+b
        spmm_gather<false, 128><<<row_grid(N_POS), blk, 0, stream>>>(
            rp1, pairs1, P3a, DD, 0, P3b, DD, 0, N_POS, dflag);       // P3b = A33@P3a
        spmm_gather<true, 128><<<row_grid(N_DOC), blk, 0, stream>>>(
            rp2, pairs2, P3b, DD, 0, AGG3, DD, 0, N_DOC, dflag);      // AGG3 = A03@relu(P3b)
        l2norm_kernel<<<row_grid(N_DOC), blk, 0, stream>>>(
            AGG3, DD, d_out, OUT3_OFF, N_DOC, dflag);
    } else {
        // ================= fallback: R5 atomic-scatter path =================
        hipMemsetAsync(S0, 0, (size_t)N_WORD * DD * 4, stream);
        spmm_kernel<false><<<spmm_grid(E11), blk, 0, stream>>>(
            a11r, a11c, a11v, f1, DD, 1, S0, DD, 0, DD, E11, dflag);
        gemm128_kernel<true><<<(N_WORD + 63) / 64, 256, 0, stream>>>(
            S0, W1_2, b1_2, S1, N_WORD, dflag);
        hipMemsetAsync(S0, 0, (size_t)N_WORD * DD * 4, stream);
        spmm_kernel<false><<<spmm_grid(E11), blk, 0, stream>>>(
            a11r, a11c, a11v, S1, DD, 0, S0, DD, 0, DD, E11, dflag);
        hipMemsetAsync(AGG1, 0, (size_t)N_DOC * DD * 4, stream);
        spmm_kernel<true><<<spmm_grid(E01), blk, 0, stream>>>(
            a01r, a01c, a01v, S0, DD, 0, AGG1, DD, 0, DD, E01, dflag);
        l2norm_kernel<<<row_grid(N_DOC), blk, 0, stream>>>(
            AGG1, DD, d_out, OUT1_OFF, N_DOC, dflag);

        hipMemsetAsync(E0, 0, (size_t)N_ENT * DD * 4, stream);
        spmm_kernel<false><<<spmm_grid(E22), blk, 0, stream>>>(
            a22r, a22c, a22v, f2, DD, 1, E0, DD, 0, DD, E22, dflag);
        gemm128_kernel<true><<<(N_ENT + 63) / 64, 256, 0, stream>>>(
            E0, W2_2, b2_2, E1, N_ENT, dflag);
        hipMemsetAsync(E0, 0, (size_t)N_ENT * DD * 4, stream);
        spmm_kernel<false><<<spmm_grid(E22), blk, 0, stream>>>(
            a22r, a22c, a22v, E1, DD, 0, E0, DD, 0, DD, E22, dflag);
        hipMemsetAsync(AGG2, 0, (size_t)N_DOC * (DD + D_WEMB) * 4, stream);
        spmm_kernel<true><<<spmm_grid(E02), blk, 0, stream>>>(
            a02r, a02c, a02v, E0, DD, 0, AGG2, DD + D_WEMB, 0, DD, E02, dflag);
        spmm_kernel<false><<<spmm_grid(E02), blk, 0, stream>>>(
            a02r, a02c, a02v, wemb, D_WEMB, 1, AGG2, DD + D_WEMB, DD, D_WEMB, E02, dflag);
        l2norm_kernel<<<row_grid(N_DOC), blk, 0, stream>>>(
            AGG2, DD + D_WEMB, d_out, OUT2_OFF, N_DOC, dflag);

        gemm_kernel<false, 60><<<1, 128, 0, stream>>>(f3, 1, W3, b3, P3a, N_POS, dflag);
        hipMemsetAsync(P3b, 0, (size_t)N_POS * DD * 4, stream);
        spmm_kernel<false><<<spmm_grid(E33), blk, 0, stream>>>(
            a33r, a33c, a33v, P3a, DD, 0, P3b, DD, 0, DD, E33, dflag);
        gemm128_kernel<true><<<1, 256, 0, stream>>>(
            P3b, W3_2, b3_2, P3a, N_POS, dflag);
        hipMemsetAsync(P3b, 0, (size_t)N_POS * DD * 4, stream);
        spmm_kernel<false><<<spmm_grid(E33), blk, 0, stream>>>(
            a33r, a33c, a33v, P3a, DD, 0, P3b, DD, 0, DD, E33, dflag);
        hipMemsetAsync(AGG3, 0, (size_t)N_DOC * DD * 4, stream);
        spmm_kernel<true><<<spmm_grid(E03), blk, 0, stream>>>(
            a03r, a03c, a03v, P3b, DD, 0, AGG3, DD, 0, DD, E03, dflag);
        l2norm_kernel<<<row_grid(N_DOC), blk, 0, stream>>>(
            AGG3, DD, d_out, OUT3_OFF, N_DOC, dflag);
    }
}

// Round 7
// 737.895 us; speedup vs baseline: 3.6973x; 1.4424x over previous
//
#include <hip/hip_runtime.h>
#include <hip/hip_bf16.h>

typedef __hip_bfloat16 bf16;

#define N_DOC   10000
#define N_WORD  20000
#define N_ENT   10000
#define N_POS   60
#define DD      128
#define D_WEMB  300
#define E11     320000
#define E22     160000
#define E33     3600
#define E01     300000
#define E02     100000
#define E03     150000

// Runtime dtype flag (ws[0]): 1 if float inputs are packed bf16, 0 if fp32.
__device__ __forceinline__ float loadf(const void* p, size_t i, int isb) {
    return isb ? __bfloat162float(((const bf16*)p)[i])
               : ((const float*)p)[i];
}
__device__ __forceinline__ float b2f(unsigned u16) {
    union { unsigned v; float f; } x; x.v = u16 << 16; return x.f;
}
__device__ __forceinline__ unsigned f2b(float f) {
    bf16 h = __float2bfloat16(f);
    union { bf16 h; unsigned short u; } x; x.h = h; return (unsigned)x.u;
}

// Detect input dtype from a randn fp32-or-bf16 buffer (see R2 notes).
__global__ void detect_kernel(const unsigned* __restrict__ probe, int* __restrict__ flag) {
    __shared__ int cnt;
    if (threadIdx.x == 0) cnt = 0;
    __syncthreads();
    int insane = 0;
    for (int i = threadIdx.x; i < 1024; i += 256) {
        float x = __uint_as_float(probe[i]);
        float a = fabsf(x);
        if (!(a > 1e-10f && a < 1e10f)) insane++;
    }
    atomicAdd(&cnt, insane);
    __syncthreads();
    if (threadIdx.x == 0) *flag = (cnt > 512) ? 1 : 0;
}

// ======================= fused 2-matrix CSR build =======================
__global__ void hist2_kernel(const int* __restrict__ rowsA, int nEA,
                             const int* __restrict__ rowsB, int nEB,
                             int nA, int* __restrict__ cnt) {
    int i = blockIdx.x * blockDim.x + threadIdx.x;
    if (i < nEA) atomicAdd(cnt + rowsA[i], 1);
    else if (i < nEA + nEB) atomicAdd(cnt + nA + rowsB[i - nEA], 1);
}

// Exclusive scan (1024 threads, wave shfl-scan + cross-wave LDS; 4 barriers/chunk).
__device__ void scan_ex(const int* __restrict__ cnt, int* __restrict__ rp, int n) {
    __shared__ int wsum[16];
    __shared__ int carry;
    int t = threadIdx.x, lane = t & 63, w = t >> 6;
    if (t == 0) carry = 0;
    __syncthreads();
    for (int base = 0; base < n; base += 1024) {
        int i = base + t;
        int x = (i < n) ? cnt[i] : 0;
        int s = x;
        #pragma unroll
        for (int off = 1; off < 64; off <<= 1) {
            int y = __shfl_up(s, off);
            if (lane >= off) s += y;
        }
        if (lane == 63) wsum[w] = s;
        __syncthreads();
        if (w == 0) {
            int v = (lane < 16) ? wsum[lane] : 0;
            #pragma unroll
            for (int off = 1; off < 16; off <<= 1) {
                int y = __shfl_up(v, off);
                if (lane >= off) v += y;
            }
            if (lane < 16) wsum[lane] = v;
        }
        __syncthreads();
        int woff = (w > 0) ? wsum[w - 1] : 0;
        if (i < n) rp[i] = carry + woff + s - x;
        __syncthreads();
        if (t == 0) carry += wsum[15];
        __syncthreads();
    }
    if (t == 0) rp[n] = carry;
}

__global__ __launch_bounds__(1024) void scan2_kernel(
        const int* __restrict__ cntA, int* __restrict__ rpA, int nA,
        const int* __restrict__ cntB, int* __restrict__ rpB, int nB) {
    scan_ex(cntA, rpA, nA);
    __syncthreads();
    scan_ex(cntB, rpB, nB);
}

__global__ void copy2_kernel(const int* __restrict__ rpA, const int* __restrict__ rpB,
                             int nA, int nB, int* __restrict__ cur) {
    int i = blockIdx.x * blockDim.x + threadIdx.x;
    if (i < nA) cur[i] = rpA[i];
    else if (i < nA + nB) cur[i] = rpB[i - nA];
}

__global__ void scatter2_kernel(const int* __restrict__ rowsA, const int* __restrict__ colsA,
                                const void* __restrict__ valsA, int nEA,
                                const int* __restrict__ rowsB, const int* __restrict__ colsB,
                                const void* __restrict__ valsB, int nEB,
                                int nA, int* __restrict__ cur,
                                int2* __restrict__ pairsA, int2* __restrict__ pairsB,
                                const int* __restrict__ dflag) {
    int i = blockIdx.x * blockDim.x + threadIdx.x;
    int isb = *dflag;
    if (i < nEA) {
        int p = atomicAdd(cur + rowsA[i], 1);
        pairsA[p] = make_int2(colsA[i], __float_as_int(loadf(valsA, i, isb)));
    } else if (i < nEA + nEB) {
        int k = i - nEA;
        int p = atomicAdd(cur + nA + rowsB[k], 1);
        pairsB[p] = make_int2(colsB[k], __float_as_int(loadf(valsB, k, isb)));
    }
}

// ======================= gather SpMM (no atomics) =======================
// dst[row, doff+0..D) = sum_e vals[e] * act(src[cols[e], 0..D)); one wave/row.
template<bool RELU, int D>
__global__ void spmm_gather(const int* __restrict__ rowptr, const int2* __restrict__ pairs,
                            const void* __restrict__ src, int sstride, int src_flagged,
                            float* __restrict__ dst, int dstride, int doff,
                            int n, const int* __restrict__ dflag) {
    constexpr int PAIRS = D / 2;
    constexpr int NS = (PAIRS + 63) / 64;
    int row = blockIdx.x * (blockDim.x >> 6) + (threadIdx.x >> 6);
    if (row >= n) return;
    int isb  = *dflag;
    int sisb = src_flagged ? isb : 0;
    int lane = threadIdx.x & 63;
    int e0 = rowptr[row], e1 = rowptr[row + 1];
    float2 acc[NS];
    #pragma unroll
    for (int s = 0; s < NS; ++s) acc[s] = make_float2(0.f, 0.f);
    if (sisb) {
        for (int e = e0; e < e1; ++e) {
            int2 p = pairs[e];
            float v = __int_as_float(p.y);
            const unsigned* sp = (const unsigned*)((const bf16*)src + (size_t)p.x * sstride);
            #pragma unroll
            for (int s = 0; s < NS; ++s) {
                int pi = lane + 64 * s;
                if (pi < PAIRS) {
                    unsigned u = sp[pi];
                    float x0 = b2f(u & 0xffffu), x1 = b2f(u >> 16);
                    if (RELU) { x0 = fmaxf(x0, 0.f); x1 = fmaxf(x1, 0.f); }
                    acc[s].x = fmaf(v, x0, acc[s].x);
                    acc[s].y = fmaf(v, x1, acc[s].y);
                }
            }
        }
    } else {
        for (int e = e0; e < e1; ++e) {
            int2 p = pairs[e];
            float v = __int_as_float(p.y);
            const float2* sp = (const float2*)((const float*)src + (size_t)p.x * sstride);
            #pragma unroll
            for (int s = 0; s < NS; ++s) {
                int pi = lane + 64 * s;
                if (pi < PAIRS) {
                    float2 x = sp[pi];
                    if (RELU) { x.x = fmaxf(x.x, 0.f); x.y = fmaxf(x.y, 0.f); }
                    acc[s].x = fmaf(v, x.x, acc[s].x);
                    acc[s].y = fmaf(v, x.y, acc[s].y);
                }
            }
        }
    }
    float2* dp = (float2*)(dst + (size_t)row * dstride + doff);
    #pragma unroll
    for (int s = 0; s < NS; ++s) {
        int pi = lane + 64 * s;
        if (pi < PAIRS) dp[pi] = acc[s];
    }
}

// ======================= atomic SpMM (ws_size fallback only) =======================
template<bool RELU>
__global__ void spmm_kernel(const int* __restrict__ rows, const int* __restrict__ cols,
                            const void* __restrict__ vals,
                            const void* __restrict__ src, int sstride, int src_flagged,
                            float* __restrict__ dst, int dstride, int doff,
                            int d, int nE, const int* __restrict__ dflag) {
    int e = blockIdx.x * (blockDim.x >> 6) + (threadIdx.x >> 6);
    if (e >= nE) return;
    int isb  = *dflag;
    int sisb = src_flagged ? isb : 0;
    int lane = threadIdx.x & 63;
    int r = rows[e];
    int c = cols[e];
    float v = loadf(vals, e, isb);
    size_t sbase = (size_t)c * sstride;
    float* dp = dst + (size_t)r * dstride + doff;
    if (sisb) {
        const unsigned* sp = (const unsigned*)((const bf16*)src + sbase);
        for (int j = 2 * lane; j < d; j += 128) {
            unsigned u = sp[j >> 1];
            float x0 = b2f(u & 0xffffu);
            float x1 = b2f(u >> 16);
            if (RELU) { x0 = fmaxf(x0, 0.f); x1 = fmaxf(x1, 0.f); }
            atomicAdd(dp + j,     v * x0);
            atomicAdd(dp + j + 1, v * x1);
        }
    } else {
        const float2* sp = (const float2*)((const float*)src + sbase);
        for (int j = 2 * lane; j < d; j += 128) {
            float2 x = sp[j >> 1];
            if (RELU) { x.x = fmaxf(x.x, 0.f); x.y = fmaxf(x.y, 0.f); }
            atomicAdd(dp + j,     v * x.x);
            atomicAdd(dp + j + 1, v * x.y);
        }
    }
}

// ======================= dense GEMMs =======================
// out[n x 128] = act(X[n x 128]) @ W[128 x 128] + b.  Big-n version (type 1/2).
template<bool RELU>
__global__ __launch_bounds__(256) void gemm128_kernel(
        const float* __restrict__ X, const void* __restrict__ W,
        const void* __restrict__ b, float* __restrict__ out, int n,
        const int* __restrict__ dflag) {
    __shared__ float Wl[128 * 128];
    int isb = *dflag;
    int tid = threadIdx.x;
    if (isb) {
        const uint2* Wg = (const uint2*)W;
        float4* Wl4 = (float4*)Wl;
        for (int idx = tid; idx < 4096; idx += 256) {
            uint2 u = Wg[idx];
            float4 vv;
            vv.x = b2f(u.x & 0xffffu);
            vv.y = b2f(u.x >> 16);
            vv.z = b2f(u.y & 0xffffu);
            vv.w = b2f(u.y >> 16);
            Wl4[idx] = vv;
        }
    } else {
        const float4* Wg = (const float4*)W;
        float4* Wl4 = (float4*)Wl;
        for (int idx = tid; idx < 4096; idx += 256) Wl4[idx] = Wg[idx];
    }
    __syncthreads();
    int j = tid & 127;
    int h = tid >> 7;
    float bj = loadf(b, j, isb);
    int row0 = blockIdx.x * 64 + h * 32;
    for (int q = 0; q < 8; ++q) {
        int gi = row0 + q * 4;
        if (gi >= n) break;
        const float4* x0 = (const float4*)(X + (size_t)gi * 128);
        const float4* x1 = x0 + 32;
        const float4* x2 = x1 + 32;
        const float4* x3 = x2 + 32;
        float a0 = bj, a1 = bj, a2 = bj, a3 = bj;
        #pragma unroll 4
        for (int k4 = 0; k4 < 32; ++k4) {
            float4 v0 = x0[k4], v1 = x1[k4], v2 = x2[k4], v3 = x3[k4];
            if (RELU) {
                v0.x = fmaxf(v0.x, 0.f); v0.y = fmaxf(v0.y, 0.f); v0.z = fmaxf(v0.z, 0.f); v0.w = fmaxf(v0.w, 0.f);
                v1.x = fmaxf(v1.x, 0.f); v1.y = fmaxf(v1.y, 0.f); v1.z = fmaxf(v1.z, 0.f); v1.w = fmaxf(v1.w, 0.f);
                v2.x = fmaxf(v2.x, 0.f); v2.y = fmaxf(v2.y, 0.f); v2.z = fmaxf(v2.z, 0.f); v2.w = fmaxf(v2.w, 0.f);
                v3.x = fmaxf(v3.x, 0.f); v3.y = fmaxf(v3.y, 0.f); v3.z = fmaxf(v3.z, 0.f); v3.w = fmaxf(v3.w, 0.f);
            }
            float w0 = Wl[(4 * k4 + 0) * 128 + j];
            float w1 = Wl[(4 * k4 + 1) * 128 + j];
            float w2 = Wl[(4 * k4 + 2) * 128 + j];
            float w3 = Wl[(4 * k4 + 3) * 128 + j];
            a0 = fmaf(v0.w, w3, fmaf(v0.z, w2, fmaf(v0.y, w1, fmaf(v0.x, w0, a0))));
            a1 = fmaf(v1.w, w3, fmaf(v1.z, w2, fmaf(v1.y, w1, fmaf(v1.x, w0, a1))));
            a2 = fmaf(v2.w, w3, fmaf(v2.z, w2, fmaf(v2.y, w1, fmaf(v2.x, w0, a2))));
            a3 = fmaf(v3.w, w3, fmaf(v3.z, w2, fmaf(v3.y, w1, fmaf(v3.x, w0, a3))));
        }
        float* o = out + (size_t)gi * 128 + j;
        o[0] = a0; o[128] = a1; o[256] = a2; o[384] = a3;
    }
}

// Row-parallel tiny GEMM (type-3, n=60): one block per row, 128 threads.
// X row staged in LDS; W read coalesced from global (L2-resident, 15-64 KB).
template<bool RELU, int K>
__global__ void rowpar_gemm(const void* __restrict__ X, int x_flagged,
                            const void* __restrict__ W, const void* __restrict__ b,
                            float* __restrict__ out, const int* __restrict__ dflag) {
    __shared__ float xr[K];
    int isb  = *dflag;
    int xisb = x_flagged ? isb : 0;
    int row = blockIdx.x;
    int j = threadIdx.x;
    if (j < K) {
        float x = loadf(X, (size_t)row * K + j, xisb);
        if (RELU) x = fmaxf(x, 0.f);
        xr[j] = x;
    }
    __syncthreads();
    float acc = loadf(b, j, isb);
    #pragma unroll 8
    for (int k = 0; k < K; ++k)
        acc = fmaf(xr[k], loadf(W, (size_t)k * 128 + j, isb), acc);
    out[(size_t)row * 128 + j] = acc;
}

// Generic small GEMM (fallback path only).
template<bool RELU, int K>
__global__ void gemm_kernel(const void* __restrict__ X, int x_flagged,
                            const void* __restrict__ W,
                            const void* __restrict__ b,
                            float* __restrict__ out, int n,
                            const int* __restrict__ dflag) {
    __shared__ float Wl[K * 128];
    int isb  = *dflag;
    int xisb = x_flagged ? isb : 0;
    int j = threadIdx.x;
    for (int idx = j; idx < K * 128; idx += 128)
        Wl[idx] = loadf(W, idx, isb);
    __syncthreads();
    float bj = loadf(b, j, isb);
    int row0 = blockIdx.x * 64;
    for (int i0 = 0; i0 < 64; i0 += 4) {
        int i = row0 + i0;
        if (i >= n) break;
        size_t r0 = (size_t)i * K;
        float a0 = bj, a1 = bj, a2 = bj, a3 = bj;
        for (int k = 0; k < K; ++k) {
            float w = Wl[k * 128 + j];
            float v0 = loadf(X, r0 + k, xisb);
            float v1 = loadf(X, r0 + K + k, xisb);
            float v2 = loadf(X, r0 + 2 * K + k, xisb);
            float v3 = loadf(X, r0 + 3 * K + k, xisb);
            if (RELU) {
                v0 = fmaxf(v0, 0.f); v1 = fmaxf(v1, 0.f);
                v2 = fmaxf(v2, 0.f); v3 = fmaxf(v3, 0.f);
            }
            a0 = fmaf(v0, w, a0);
            a1 = fmaf(v1, w, a1);
            a2 = fmaf(v2, w, a2);
            a3 = fmaf(v3, w, a3);
        }
        float* o = out + (size_t)i * 128 + j;
        o[0] = a0; o[128] = a1; o[256] = a2; o[384] = a3;
    }
}

// out[elem_off + row*d + j] = agg[row,j] / (||agg[row,:]|| + 1e-9); one wave/row.
__global__ void l2norm_kernel(const float* __restrict__ agg, int d,
                              void* __restrict__ out, size_t elem_off, int n,
                              const int* __restrict__ dflag) {
    int row = blockIdx.x * (blockDim.x >> 6) + (threadIdx.x >> 6);
    if (row >= n) return;
    int isb  = *dflag;
    int lane = threadIdx.x & 63;
    const float2* a2 = (const float2*)(agg + (size_t)row * d);
    float ss = 0.f;
    for (int j = 2 * lane; j < d; j += 128) {
        float2 x = a2[j >> 1];
        ss += x.x * x.x + x.y * x.y;
    }
    #pragma unroll
    for (int off = 32; off > 0; off >>= 1) ss += __shfl_down(ss, off);
    ss = __shfl(ss, 0);
    float inv = 1.0f / (sqrtf(ss) + 1e-9f);
    size_t bbase = elem_off + (size_t)row * d;
    if (isb) {
        unsigned* o = (unsigned*)((bf16*)out + bbase);
        for (int j = 2 * lane; j < d; j += 128) {
            float2 x = a2[j >> 1];
            o[j >> 1] = f2b(x.x * inv) | (f2b(x.y * inv) << 16);
        }
    } else {
        float2* o = (float2*)((float*)out + bbase);
        for (int j = 2 * lane; j < d; j += 128) {
            float2 x = a2[j >> 1];
            o[j >> 1] = make_float2(x.x * inv, x.y * inv);
        }
    }
}

static inline int spmm_grid(int nE) { return (nE + 3) / 4; }
static inline int row_grid(int n)   { return (n + 3) / 4; }

// Fused per-phase CSR build for two matrices A,B sharing one cursor block.
static void build2(hipStream_t stream,
                   const int* rowsA, const int* colsA, const void* valsA, int nA, int nEA,
                   const int* rowsB, const int* colsB, const void* valsB, int nB, int nEB,
                   int* rpA, int* rpB, int* curAB, int2* pairsA, int2* pairsB,
                   const int* dflag) {
    int nE = nEA + nEB;
    hipMemsetAsync(curAB, 0, (size_t)(nA + nB) * 4, stream);
    hist2_kernel<<<(nE + 255) / 256, 256, 0, stream>>>(rowsA, nEA, rowsB, nEB, nA, curAB);
    scan2_kernel<<<1, 1024, 0, stream>>>(curAB, rpA, nA, curAB + nA, rpB, nB);
    copy2_kernel<<<(nA + nB + 255) / 256, 256, 0, stream>>>(rpA, rpB, nA, nB, curAB);
    scatter2_kernel<<<(nE + 255) / 256, 256, 0, stream>>>(
        rowsA, colsA, valsA, nEA, rowsB, colsB, valsB, nEB, nA, curAB, pairsA, pairsB, dflag);
}

extern "C" void kernel_launch(void* const* d_in, const int* in_sizes, int n_in,
                              void* d_out, int out_size, void* d_ws, size_t ws_size,
                              hipStream_t stream) {
    const void* f1   = d_in[0];
    const void* f2   = d_in[1];
    const void* f3   = d_in[2];
    const void* wemb = d_in[3];
    const int*  a11r = (const int*)d_in[4];
    const int*  a11c = (const int*)d_in[5];
    const void* a11v = d_in[6];
    const int*  a22r = (const int*)d_in[7];
    const int*  a22c = (const int*)d_in[8];
    const void* a22v = d_in[9];
    const int*  a33r = (const int*)d_in[10];
    const int*  a33c = (const int*)d_in[11];
    const void* a33v = d_in[12];
    const int*  a01r = (const int*)d_in[13];
    const int*  a01c = (const int*)d_in[14];
    const void* a01v = d_in[15];
    const int*  a02r = (const int*)d_in[16];
    const int*  a02c = (const int*)d_in[17];
    const void* a02v = d_in[18];
    const int*  a03r = (const int*)d_in[19];
    const int*  a03c = (const int*)d_in[20];
    const void* a03v = d_in[21];
    const void* W3   = d_in[22];
    const void* b3   = d_in[23];
    const void* W1_2 = d_in[24];
    const void* b1_2 = d_in[25];
    const void* W2_2 = d_in[26];
    const void* b2_2 = d_in[27];
    const void* W3_2 = d_in[28];
    const void* b3_2 = d_in[29];

    int*   dflag = (int*)d_ws;
    float* base  = (float*)d_ws + 16;       // dense buffers start 64 B in
    float* S0   = base;                     // 20000*128
    float* S1   = base + 2560000;           // 20000*128
    float* AGG1 = S1;                       // 10000*128 (S1 dead when used)
    float* E0   = base;                     // 10000*128
    float* E1   = base + 1280000;           // 10000*128
    float* AGG2 = base + 1280000;           // 10000*428 (E1 dead when used)
    float* P3a  = base;                     // 60*128
    float* P3b  = base + 7680;              // 60*128
    float* AGG3 = base + 15360;             // 10000*128

    // CSR region after dense peak; per-phase layout (int counts all even ->
    // pairs stay 8B-aligned): [rpA(nA+1) | rpB(nB+1) | curAB(nA+nB) | pairsA | pairsB]
    int* I = (int*)(base + 5560000);
    const size_t WS_NEEDED = 64 + 22240000ull + 240008ull + 4960000ull; // phase-1 peak ~27.44 MB

    const size_t OUT1_OFF = 0;
    const size_t OUT2_OFF = (size_t)N_DOC * DD;                       // 1,280,000
    const size_t OUT3_OFF = OUT2_OFF + (size_t)N_DOC * (DD + D_WEMB); // 5,560,000

    dim3 blk(256);
    detect_kernel<<<1, 256, 0, stream>>>((const unsigned*)f1, dflag);

    if (ws_size >= WS_NEEDED) {
        // ================= CSR gather path =================
        // ---------------- type 1 (words): A=A11 (20000), B=A01 (10000) ----------------
        {
            int* rpA = I; int* rpB = rpA + (N_WORD + 1); int* cur = rpB + (N_DOC + 1);
            int2* pA = (int2*)(cur + N_WORD + N_DOC); int2* pB = pA + E11;
            build2(stream, a11r, a11c, a11v, N_WORD, E11,
                   a01r, a01c, a01v, N_DOC, E01, rpA, rpB, cur, pA, pB, dflag);
            spmm_gather<false, 128><<<row_grid(N_WORD), blk, 0, stream>>>(
                rpA, pA, f1, DD, 1, S0, DD, 0, N_WORD, dflag);        // S0 = A11@f1
            gemm128_kernel<true><<<(N_WORD + 63) / 64, 256, 0, stream>>>(
                S0, W1_2, b1_2, S1, N_WORD, dflag);                   // S1 = relu(S0)@W+b
            spmm_gather<false, 128><<<row_grid(N_WORD), blk, 0, stream>>>(
                rpA, pA, S1, DD, 0, S0, DD, 0, N_WORD, dflag);        // S0 = A11@S1
            spmm_gather<true, 128><<<row_grid(N_DOC), blk, 0, stream>>>(
                rpB, pB, S0, DD, 0, AGG1, DD, 0, N_DOC, dflag);       // AGG1 = A01@relu(S0)
            l2norm_kernel<<<row_grid(N_DOC), blk, 0, stream>>>(
                AGG1, DD, d_out, OUT1_OFF, N_DOC, dflag);
        }
        // ---------------- type 2 (entities): A=A22 (10000), B=A02 (10000) ----------------
        {
            int* rpA = I; int* rpB = rpA + (N_ENT + 1); int* cur = rpB + (N_DOC + 1);
            int2* pA = (int2*)(cur + N_ENT + N_DOC); int2* pB = pA + E22;
            build2(stream, a22r, a22c, a22v, N_ENT, E22,
                   a02r, a02c, a02v, N_DOC, E02, rpA, rpB, cur, pA, pB, dflag);
            spmm_gather<false, 128><<<row_grid(N_ENT), blk, 0, stream>>>(
                rpA, pA, f2, DD, 1, E0, DD, 0, N_ENT, dflag);         // E0 = A22@f2
            gemm128_kernel<true><<<(N_ENT + 63) / 64, 256, 0, stream>>>(
                E0, W2_2, b2_2, E1, N_ENT, dflag);                    // E1 = relu(E0)@W+b
            spmm_gather<false, 128><<<row_grid(N_ENT), blk, 0, stream>>>(
                rpA, pA, E1, DD, 0, E0, DD, 0, N_ENT, dflag);         // E0 = A22@E1
            spmm_gather<true, 128><<<row_grid(N_DOC), blk, 0, stream>>>(
                rpB, pB, E0, DD, 0, AGG2, DD + D_WEMB, 0, N_DOC, dflag);
            spmm_gather<false, 300><<<row_grid(N_DOC), blk, 0, stream>>>(
                rpB, pB, wemb, D_WEMB, 1, AGG2, DD + D_WEMB, DD, N_DOC, dflag);
            l2norm_kernel<<<row_grid(N_DOC), blk, 0, stream>>>(
                AGG2, DD + D_WEMB, d_out, OUT2_OFF, N_DOC, dflag);
        }
        // ---------------- type 3 (POS): A=A33 (60), B=A03 (10000) ----------------
        {
            int* rpA = I; int* rpB = rpA + (N_POS + 1); int* cur = rpB + (N_DOC + 1);
            int2* pA = (int2*)(cur + N_POS + N_DOC); int2* pB = pA + E33;
            build2(stream, a33r, a33c, a33v, N_POS, E33,
                   a03r, a03c, a03v, N_DOC, E03, rpA, rpB, cur, pA, pB, dflag);
            rowpar_gemm<false, 60><<<N_POS, 128, 0, stream>>>(
                f3, 1, W3, b3, P3a, dflag);                           // P3a = f3@W3+b3
            spmm_gather<false, 128><<<row_grid(N_POS), blk, 0, stream>>>(
                rpA, pA, P3a, DD, 0, P3b, DD, 0, N_POS, dflag);       // P3b = A33@P3a
            rowpar_gemm<true, 128><<<N_POS, 128, 0, stream>>>(
                P3b, 0, W3_2, b3_2, P3a, dflag);                      // P3a = relu(P3b)@W+b
            spmm_gather<false, 128><<<row_grid(N_POS), blk, 0, stream>>>(
                rpA, pA, P3a, DD, 0, P3b, DD, 0, N_POS, dflag);       // P3b = A33@P3a
            spmm_gather<true, 128><<<row_grid(N_DOC), blk, 0, stream>>>(
                rpB, pB, P3b, DD, 0, AGG3, DD, 0, N_DOC, dflag);      // AGG3 = A03@relu(P3b)
            l2norm_kernel<<<row_grid(N_DOC), blk, 0, stream>>>(
                AGG3, DD, d_out, OUT3_OFF, N_DOC, dflag);
        }
    } else {
        // ================= fallback: atomic-scatter path =================
        hipMemsetAsync(S0, 0, (size_t)N_WORD * DD * 4, stream);
        spmm_kernel<false><<<spmm_grid(E11), blk, 0, stream>>>(
            a11r, a11c, a11v, f1, DD, 1, S0, DD, 0, DD, E11, dflag);
        gemm128_kernel<true><<<(N_WORD + 63) / 64, 256, 0, stream>>>(
            S0, W1_2, b1_2, S1, N_WORD, dflag);
        hipMemsetAsync(S0, 0, (size_t)N_WORD * DD * 4, stream);
        spmm_kernel<false><<<spmm_grid(E11), blk, 0, stream>>>(
            a11r, a11c, a11v, S1, DD, 0, S0, DD, 0, DD, E11, dflag);
        hipMemsetAsync(AGG1, 0, (size_t)N_DOC * DD * 4, stream);
        spmm_kernel<true><<<spmm_grid(E01), blk, 0, stream>>>(
            a01r, a01c, a01v, S0, DD, 0, AGG1, DD, 0, DD, E01, dflag);
        l2norm_kernel<<<row_grid(N_DOC), blk, 0, stream>>>(
            AGG1, DD, d_out, OUT1_OFF, N_DOC, dflag);

        hipMemsetAsync(E0, 0, (size_t)N_ENT * DD * 4, stream);
        spmm_kernel<false><<<spmm_grid(E22), blk, 0, stream>>>(
            a22r, a22c, a22v, f2, DD, 1, E0, DD, 0, DD, E22, dflag);
        gemm128_kernel<true><<<(N_ENT + 63) / 64, 256, 0, stream>>>(
            E0, W2_2, b2_2, E1, N_ENT, dflag);
        hipMemsetAsync(E0, 0, (size_t)N_ENT * DD * 4, stream);
        spmm_kernel<false><<<spmm_grid(E22), blk, 0, stream>>>(
            a22r, a22c, a22v, E1, DD, 0, E0, DD, 0, DD, E22, dflag);
        hipMemsetAsync(AGG2, 0, (size_t)N_DOC * (DD + D_WEMB) * 4, stream);
        spmm_kernel<true><<<spmm_grid(E02), blk, 0, stream>>>(
            a02r, a02c, a02v, E0, DD, 0, AGG2, DD + D_WEMB, 0, DD, E02, dflag);
        spmm_kernel<false><<<spmm_grid(E02), blk, 0, stream>>>(
            a02r, a02c, a02v, wemb, D_WEMB, 1, AGG2, DD + D_WEMB, DD, D_WEMB, E02, dflag);
        l2norm_kernel<<<row_grid(N_DOC), blk, 0, stream>>>(
            AGG2, DD + D_WEMB, d_out, OUT2_OFF, N_DOC, dflag);

        gemm_kernel<false, 60><<<1, 128, 0, stream>>>(f3, 1, W3, b3, P3a, N_POS, dflag);
        hipMemsetAsync(P3b, 0, (size_t)N_POS * DD * 4, stream);
        spmm_kernel<false><<<spmm_grid(E33), blk, 0, stream>>>(
            a33r, a33c, a33v, P3a, DD, 0, P3b, DD, 0, DD, E33, dflag);
        gemm128_kernel<true><<<1, 256, 0, stream>>>(
            P3b, W3_2, b3_2, P3a, N_POS, dflag);
        hipMemsetAsync(P3b, 0, (size_t)N_POS * DD * 4, stream);
        spmm_kernel<false><<<spmm_grid(E33), blk, 0, stream>>>(
            a33r, a33c, a33v, P3a, DD, 0, P3b, DD, 0, DD, E33, dflag);
        hipMemsetAsync(AGG3, 0, (size_t)N_DOC * DD * 4, stream);
        spmm_kernel<true><<<spmm_grid(E03), blk, 0, stream>>>(
            a03r, a03c, a03v, P3b, DD, 0, AGG3, DD, 0, DD, E03, dflag);
        l2norm_kernel<<<row_grid(N_DOC), blk, 0, stream>>>(
            AGG3, DD, d_out, OUT3_OFF, N_DOC, dflag);
    }
}

// Round 8
// 635.971 us; speedup vs baseline: 4.2898x; 1.1603x over previous
//
#include <hip/hip_runtime.h>
#include <hip/hip_bf16.h>

typedef __hip_bfloat16 bf16;

#define N_DOC   10000
#define N_WORD  20000
#define N_ENT   10000
#define N_POS   60
#define DD      128
#define D_WEMB  300
#define E11     320000
#define E22     160000
#define E33     3600
#define E01     300000
#define E02     100000
#define E03     150000

// Runtime dtype flag (ws[0]): 1 if float inputs are packed bf16, 0 if fp32.
__device__ __forceinline__ float loadf(const void* p, size_t i, int isb) {
    return isb ? __bfloat162float(((const bf16*)p)[i])
               : ((const float*)p)[i];
}
__device__ __forceinline__ float b2f(unsigned u16) {
    union { unsigned v; float f; } x; x.v = u16 << 16; return x.f;
}
__device__ __forceinline__ unsigned f2b(float f) {
    bf16 h = __float2bfloat16(f);
    union { bf16 h; unsigned short u; } x; x.h = h; return (unsigned)x.u;
}

// Detect input dtype from a randn fp32-or-bf16 buffer (see R2 notes).
__global__ void detect_kernel(const unsigned* __restrict__ probe, int* __restrict__ flag) {
    __shared__ int cnt;
    if (threadIdx.x == 0) cnt = 0;
    __syncthreads();
    int insane = 0;
    for (int i = threadIdx.x; i < 1024; i += 256) {
        float x = __uint_as_float(probe[i]);
        float a = fabsf(x);
        if (!(a > 1e-10f && a < 1e10f)) insane++;
    }
    atomicAdd(&cnt, insane);
    __syncthreads();
    if (threadIdx.x == 0) *flag = (cnt > 512) ? 1 : 0;
}

// ======================= fused 2-matrix CSR build =======================
__global__ void hist2_kernel(const int* __restrict__ rowsA, int nEA,
                             const int* __restrict__ rowsB, int nEB,
                             int nA, int* __restrict__ cnt) {
    int i = blockIdx.x * blockDim.x + threadIdx.x;
    if (i < nEA) atomicAdd(cnt + rowsA[i], 1);
    else if (i < nEA + nEB) atomicAdd(cnt + nA + rowsB[i - nEA], 1);
}

// Exclusive scan (1024 threads, wave shfl-scan + cross-wave LDS).
__device__ void scan_ex(const int* __restrict__ cnt, int* __restrict__ rp, int n) {
    __shared__ int wsum[16];
    __shared__ int carry;
    int t = threadIdx.x, lane = t & 63, w = t >> 6;
    if (t == 0) carry = 0;
    __syncthreads();
    for (int base = 0; base < n; base += 1024) {
        int i = base + t;
        int x = (i < n) ? cnt[i] : 0;
        int s = x;
        #pragma unroll
        for (int off = 1; off < 64; off <<= 1) {
            int y = __shfl_up(s, off);
            if (lane >= off) s += y;
        }
        if (lane == 63) wsum[w] = s;
        __syncthreads();
        if (w == 0) {
            int v = (lane < 16) ? wsum[lane] : 0;
            #pragma unroll
            for (int off = 1; off < 16; off <<= 1) {
                int y = __shfl_up(v, off);
                if (lane >= off) v += y;
            }
            if (lane < 16) wsum[lane] = v;
        }
        __syncthreads();
        int woff = (w > 0) ? wsum[w - 1] : 0;
        if (i < n) rp[i] = carry + woff + s - x;
        __syncthreads();
        if (t == 0) carry += wsum[15];
        __syncthreads();
    }
    if (t == 0) rp[n] = carry;
}

__global__ __launch_bounds__(1024) void scan2_kernel(
        const int* __restrict__ cntA, int* __restrict__ rpA, int nA,
        const int* __restrict__ cntB, int* __restrict__ rpB, int nB) {
    scan_ex(cntA, rpA, nA);
    __syncthreads();
    scan_ex(cntB, rpB, nB);
}

__global__ void copy2_kernel(const int* __restrict__ rpA, const int* __restrict__ rpB,
                             int nA, int nB, int* __restrict__ cur) {
    int i = blockIdx.x * blockDim.x + threadIdx.x;
    if (i < nA) cur[i] = rpA[i];
    else if (i < nA + nB) cur[i] = rpB[i - nA];
}

__global__ void scatter2_kernel(const int* __restrict__ rowsA, const int* __restrict__ colsA,
                                const void* __restrict__ valsA, int nEA,
                                const int* __restrict__ rowsB, const int* __restrict__ colsB,
                                const void* __restrict__ valsB, int nEB,
                                int nA, int* __restrict__ cur,
                                int2* __restrict__ pairsA, int2* __restrict__ pairsB,
                                const int* __restrict__ dflag) {
    int i = blockIdx.x * blockDim.x + threadIdx.x;
    int isb = *dflag;
    if (i < nEA) {
        int p = atomicAdd(cur + rowsA[i], 1);
        pairsA[p] = make_int2(colsA[i], __float_as_int(loadf(valsA, i, isb)));
    } else if (i < nEA + nEB) {
        int k = i - nEA;
        int p = atomicAdd(cur + nA + rowsB[k], 1);
        pairsB[p] = make_int2(colsB[k], __float_as_int(loadf(valsB, k, isb)));
    }
}

// ======================= gather SpMM (no atomics) =======================
// dst[row, doff+0..D) = sum_e vals[e] * act(src[cols[e], 0..D)); one wave/row.
// 2-edge unroll with dual accumulators for memory-level parallelism.
template<bool RELU, int D>
__global__ void spmm_gather(const int* __restrict__ rowptr, const int2* __restrict__ pairs,
                            const void* __restrict__ src, int sstride, int src_flagged,
                            float* __restrict__ dst, int dstride, int doff,
                            int n, const int* __restrict__ dflag) {
    constexpr int PAIRS = D / 2;
    constexpr int NS = (PAIRS + 63) / 64;
    int row = blockIdx.x * (blockDim.x >> 6) + (threadIdx.x >> 6);
    if (row >= n) return;
    int isb  = *dflag;
    int sisb = src_flagged ? isb : 0;
    int lane = threadIdx.x & 63;
    int e0 = rowptr[row], e1 = rowptr[row + 1];
    float2 acc[NS], acc2[NS];
    #pragma unroll
    for (int s = 0; s < NS; ++s) { acc[s] = make_float2(0.f, 0.f); acc2[s] = make_float2(0.f, 0.f); }
    if (sisb) {
        int e = e0;
        for (; e + 2 <= e1; e += 2) {
            int2 p0 = pairs[e], p1 = pairs[e + 1];
            float v0 = __int_as_float(p0.y), v1 = __int_as_float(p1.y);
            const unsigned* s0 = (const unsigned*)((const bf16*)src + (size_t)p0.x * sstride);
            const unsigned* s1 = (const unsigned*)((const bf16*)src + (size_t)p1.x * sstride);
            #pragma unroll
            for (int s = 0; s < NS; ++s) {
                int pi = lane + 64 * s;
                if (pi < PAIRS) {
                    unsigned u0 = s0[pi], u1 = s1[pi];
                    float a0 = b2f(u0 & 0xffffu), a1 = b2f(u0 >> 16);
                    float c0 = b2f(u1 & 0xffffu), c1 = b2f(u1 >> 16);
                    if (RELU) { a0 = fmaxf(a0, 0.f); a1 = fmaxf(a1, 0.f);
                                c0 = fmaxf(c0, 0.f); c1 = fmaxf(c1, 0.f); }
                    acc[s].x  = fmaf(v0, a0, acc[s].x);
                    acc[s].y  = fmaf(v0, a1, acc[s].y);
                    acc2[s].x = fmaf(v1, c0, acc2[s].x);
                    acc2[s].y = fmaf(v1, c1, acc2[s].y);
                }
            }
        }
        if (e < e1) {
            int2 p = pairs[e];
            float v = __int_as_float(p.y);
            const unsigned* sp = (const unsigned*)((const bf16*)src + (size_t)p.x * sstride);
            #pragma unroll
            for (int s = 0; s < NS; ++s) {
                int pi = lane + 64 * s;
                if (pi < PAIRS) {
                    unsigned u = sp[pi];
                    float x0 = b2f(u & 0xffffu), x1 = b2f(u >> 16);
                    if (RELU) { x0 = fmaxf(x0, 0.f); x1 = fmaxf(x1, 0.f); }
                    acc[s].x = fmaf(v, x0, acc[s].x);
                    acc[s].y = fmaf(v, x1, acc[s].y);
                }
            }
        }
    } else {
        int e = e0;
        for (; e + 2 <= e1; e += 2) {
            int2 p0 = pairs[e], p1 = pairs[e + 1];
            float v0 = __int_as_float(p0.y), v1 = __int_as_float(p1.y);
            const float2* s0 = (const float2*)((const float*)src + (size_t)p0.x * sstride);
            const float2* s1 = (const float2*)((const float*)src + (size_t)p1.x * sstride);
            #pragma unroll
            for (int s = 0; s < NS; ++s) {
                int pi = lane + 64 * s;
                if (pi < PAIRS) {
                    float2 x = s0[pi], y = s1[pi];
                    if (RELU) { x.x = fmaxf(x.x, 0.f); x.y = fmaxf(x.y, 0.f);
                                y.x = fmaxf(y.x, 0.f); y.y = fmaxf(y.y, 0.f); }
                    acc[s].x  = fmaf(v0, x.x, acc[s].x);
                    acc[s].y  = fmaf(v0, x.y, acc[s].y);
                    acc2[s].x = fmaf(v1, y.x, acc2[s].x);
                    acc2[s].y = fmaf(v1, y.y, acc2[s].y);
                }
            }
        }
        if (e < e1) {
            int2 p = pairs[e];
            float v = __int_as_float(p.y);
            const float2* sp = (const float2*)((const float*)src + (size_t)p.x * sstride);
            #pragma unroll
            for (int s = 0; s < NS; ++s) {
                int pi = lane + 64 * s;
                if (pi < PAIRS) {
                    float2 x = sp[pi];
                    if (RELU) { x.x = fmaxf(x.x, 0.f); x.y = fmaxf(x.y, 0.f); }
                    acc[s].x = fmaf(v, x.x, acc[s].x);
                    acc[s].y = fmaf(v, x.y, acc[s].y);
                }
            }
        }
    }
    float2* dp = (float2*)(dst + (size_t)row * dstride + doff);
    #pragma unroll
    for (int s = 0; s < NS; ++s) {
        int pi = lane + 64 * s;
        if (pi < PAIRS) dp[pi] = make_float2(acc[s].x + acc2[s].x, acc[s].y + acc2[s].y);
    }
}

// ======================= atomic SpMM (ws_size fallback only) =======================
template<bool RELU>
__global__ void spmm_kernel(const int* __restrict__ rows, const int* __restrict__ cols,
                            const void* __restrict__ vals,
                            const void* __restrict__ src, int sstride, int src_flagged,
                            float* __restrict__ dst, int dstride, int doff,
                            int d, int nE, const int* __restrict__ dflag) {
    int e = blockIdx.x * (blockDim.x >> 6) + (threadIdx.x >> 6);
    if (e >= nE) return;
    int isb  = *dflag;
    int sisb = src_flagged ? isb : 0;
    int lane = threadIdx.x & 63;
    int r = rows[e];
    int c = cols[e];
    float v = loadf(vals, e, isb);
    size_t sbase = (size_t)c * sstride;
    float* dp = dst + (size_t)r * dstride + doff;
    if (sisb) {
        const unsigned* sp = (const unsigned*)((const bf16*)src + sbase);
        for (int j = 2 * lane; j < d; j += 128) {
            unsigned u = sp[j >> 1];
            float x0 = b2f(u & 0xffffu);
            float x1 = b2f(u >> 16);
            if (RELU) { x0 = fmaxf(x0, 0.f); x1 = fmaxf(x1, 0.f); }
            atomicAdd(dp + j,     v * x0);
            atomicAdd(dp + j + 1, v * x1);
        }
    } else {
        const float2* sp = (const float2*)((const float*)src + sbase);
        for (int j = 2 * lane; j < d; j += 128) {
            float2 x = sp[j >> 1];
            if (RELU) { x.x = fmaxf(x.x, 0.f); x.y = fmaxf(x.y, 0.f); }
            atomicAdd(dp + j,     v * x.x);
            atomicAdd(dp + j + 1, v * x.y);
        }
    }
}

// ======================= dense GEMMs =======================
// out[n x 128] = act(X[n x 128]) @ W[128 x 128] + b.
// 32-column W tile in 16 KB LDS (8+ blocks/CU); 2D grid (row tiles x 4 col tiles).
// 256 threads: j = tid&31 (col in tile), g = tid>>5 (8 row groups x 8 rows).
template<bool RELU>
__global__ __launch_bounds__(256) void gemm_tile(
        const float* __restrict__ X, const void* __restrict__ W,
        const void* __restrict__ b, float* __restrict__ out, int n,
        const int* __restrict__ dflag) {
    __shared__ float Wl[128 * 32];
    int isb = *dflag;
    int tid = threadIdx.x;
    int jc = blockIdx.y * 32;
    if (isb) {
        const uint2* Wg = (const uint2*)W;            // 4 bf16 per uint2, row = 32 uint2
        float4* Wl4 = (float4*)Wl;
        for (int vidx = tid; vidx < 1024; vidx += 256) {
            int k = vidx >> 3, jl4 = vidx & 7;
            uint2 u = Wg[k * 32 + (jc >> 2) + jl4];
            float4 vv;
            vv.x = b2f(u.x & 0xffffu);
            vv.y = b2f(u.x >> 16);
            vv.z = b2f(u.y & 0xffffu);
            vv.w = b2f(u.y >> 16);
            Wl4[vidx] = vv;
        }
    } else {
        const float4* Wg = (const float4*)W;          // row = 32 float4
        float4* Wl4 = (float4*)Wl;
        for (int vidx = tid; vidx < 1024; vidx += 256) {
            int k = vidx >> 3, jl4 = vidx & 7;
            Wl4[vidx] = Wg[k * 32 + (jc >> 2) + jl4];
        }
    }
    __syncthreads();
    int j = tid & 31;
    int g = tid >> 5;
    float bj = loadf(b, jc + j, isb);
    int i0 = blockIdx.x * 64 + g * 8;
    float a[8];
    #pragma unroll
    for (int r = 0; r < 8; ++r) a[r] = bj;
    const float4* xp = (const float4*)(X + (size_t)i0 * 128);   // row r at xp + r*32
    #pragma unroll 2
    for (int k4 = 0; k4 < 32; ++k4) {
        float w0 = Wl[(4 * k4 + 0) * 32 + j];
        float w1 = Wl[(4 * k4 + 1) * 32 + j];
        float w2 = Wl[(4 * k4 + 2) * 32 + j];
        float w3 = Wl[(4 * k4 + 3) * 32 + j];
        #pragma unroll
        for (int r = 0; r < 8; ++r) {
            float4 v = xp[r * 32 + k4];
            if (RELU) {
                v.x = fmaxf(v.x, 0.f); v.y = fmaxf(v.y, 0.f);
                v.z = fmaxf(v.z, 0.f); v.w = fmaxf(v.w, 0.f);
            }
            a[r] = fmaf(v.w, w3, fmaf(v.z, w2, fmaf(v.y, w1, fmaf(v.x, w0, a[r]))));
        }
    }
    #pragma unroll
    for (int r = 0; r < 8; ++r) {
        int i = i0 + r;
        if (i < n) out[(size_t)i * 128 + jc + j] = a[r];
    }
}

// Legacy big-LDS GEMM (fallback path only).
template<bool RELU>
__global__ __launch_bounds__(256) void gemm128_kernel(
        const float* __restrict__ X, const void* __restrict__ W,
        const void* __restrict__ b, float* __restrict__ out, int n,
        const int* __restrict__ dflag) {
    __shared__ float Wl[128 * 128];
    int isb = *dflag;
    int tid = threadIdx.x;
    if (isb) {
        const uint2* Wg = (const uint2*)W;
        float4* Wl4 = (float4*)Wl;
        for (int idx = tid; idx < 4096; idx += 256) {
            uint2 u = Wg[idx];
            float4 vv;
            vv.x = b2f(u.x & 0xffffu);
            vv.y = b2f(u.x >> 16);
            vv.z = b2f(u.y & 0xffffu);
            vv.w = b2f(u.y >> 16);
            Wl4[idx] = vv;
        }
    } else {
        const float4* Wg = (const float4*)W;
        float4* Wl4 = (float4*)Wl;
        for (int idx = tid; idx < 4096; idx += 256) Wl4[idx] = Wg[idx];
    }
    __syncthreads();
    int j = tid & 127;
    int h = tid >> 7;
    float bj = loadf(b, j, isb);
    int row0 = blockIdx.x * 64 + h * 32;
    for (int q = 0; q < 8; ++q) {
        int gi = row0 + q * 4;
        if (gi >= n) break;
        const float4* x0 = (const float4*)(X + (size_t)gi * 128);
        const float4* x1 = x0 + 32;
        const float4* x2 = x1 + 32;
        const float4* x3 = x2 + 32;
        float a0 = bj, a1 = bj, a2 = bj, a3 = bj;
        #pragma unroll 4
        for (int k4 = 0; k4 < 32; ++k4) {
            float4 v0 = x0[k4], v1 = x1[k4], v2 = x2[k4], v3 = x3[k4];
            if (RELU) {
                v0.x = fmaxf(v0.x, 0.f); v0.y = fmaxf(v0.y, 0.f); v0.z = fmaxf(v0.z, 0.f); v0.w = fmaxf(v0.w, 0.f);
                v1.x = fmaxf(v1.x, 0.f); v1.y = fmaxf(v1.y, 0.f); v1.z = fmaxf(v1.z, 0.f); v1.w = fmaxf(v1.w, 0.f);
                v2.x = fmaxf(v2.x, 0.f); v2.y = fmaxf(v2.y, 0.f); v2.z = fmaxf(v2.z, 0.f); v2.w = fmaxf(v2.w, 0.f);
                v3.x = fmaxf(v3.x, 0.f); v3.y = fmaxf(v3.y, 0.f); v3.z = fmaxf(v3.z, 0.f); v3.w = fmaxf(v3.w, 0.f);
            }
            float w0 = Wl[(4 * k4 + 0) * 128 + j];
            float w1 = Wl[(4 * k4 + 1) * 128 + j];
            float w2 = Wl[(4 * k4 + 2) * 128 + j];
            float w3 = Wl[(4 * k4 + 3) * 128 + j];
            a0 = fmaf(v0.w, w3, fmaf(v0.z, w2, fmaf(v0.y, w1, fmaf(v0.x, w0, a0))));
            a1 = fmaf(v1.w, w3, fmaf(v1.z, w2, fmaf(v1.y, w1, fmaf(v1.x, w0, a1))));
            a2 = fmaf(v2.w, w3, fmaf(v2.z, w2, fmaf(v2.y, w1, fmaf(v2.x, w0, a2))));
            a3 = fmaf(v3.w, w3, fmaf(v3.z, w2, fmaf(v3.y, w1, fmaf(v3.x, w0, a3))));
        }
        float* o = out + (size_t)gi * 128 + j;
        o[0] = a0; o[128] = a1; o[256] = a2; o[384] = a3;
    }
}

// Row-parallel tiny GEMM (type-3, n=60): one block per row, 128 threads.
template<bool RELU, int K>
__global__ void rowpar_gemm(const void* __restrict__ X, int x_flagged,
                            const void* __restrict__ W, const void* __restrict__ b,
                            float* __restrict__ out, const int* __restrict__ dflag) {
    __shared__ float xr[K];
    int isb  = *dflag;
    int xisb = x_flagged ? isb : 0;
    int row = blockIdx.x;
    int j = threadIdx.x;
    if (j < K) {
        float x = loadf(X, (size_t)row * K + j, xisb);
        if (RELU) x = fmaxf(x, 0.f);
        xr[j] = x;
    }
    __syncthreads();
    float acc = loadf(b, j, isb);
    #pragma unroll 8
    for (int k = 0; k < K; ++k)
        acc = fmaf(xr[k], loadf(W, (size_t)k * 128 + j, isb), acc);
    out[(size_t)row * 128 + j] = acc;
}

// Generic small GEMM (fallback path only).
template<bool RELU, int K>
__global__ void gemm_kernel(const void* __restrict__ X, int x_flagged,
                            const void* __restrict__ W,
                            const void* __restrict__ b,
                            float* __restrict__ out, int n,
                            const int* __restrict__ dflag) {
    __shared__ float Wl[K * 128];
    int isb  = *dflag;
    int xisb = x_flagged ? isb : 0;
    int j = threadIdx.x;
    for (int idx = j; idx < K * 128; idx += 128)
        Wl[idx] = loadf(W, idx, isb);
    __syncthreads();
    float bj = loadf(b, j, isb);
    int row0 = blockIdx.x * 64;
    for (int i0 = 0; i0 < 64; i0 += 4) {
        int i = row0 + i0;
        if (i >= n) break;
        size_t r0 = (size_t)i * K;
        float a0 = bj, a1 = bj, a2 = bj, a3 = bj;
        for (int k = 0; k < K; ++k) {
            float w = Wl[k * 128 + j];
            float v0 = loadf(X, r0 + k, xisb);
            float v1 = loadf(X, r0 + K + k, xisb);
            float v2 = loadf(X, r0 + 2 * K + k, xisb);
            float v3 = loadf(X, r0 + 3 * K + k, xisb);
            if (RELU) {
                v0 = fmaxf(v0, 0.f); v1 = fmaxf(v1, 0.f);
                v2 = fmaxf(v2, 0.f); v3 = fmaxf(v3, 0.f);
            }
            a0 = fmaf(v0, w, a0);
            a1 = fmaf(v1, w, a1);
            a2 = fmaf(v2, w, a2);
            a3 = fmaf(v3, w, a3);
        }
        float* o = out + (size_t)i * 128 + j;
        o[0] = a0; o[128] = a1; o[256] = a2; o[384] = a3;
    }
}

// out[elem_off + row*d + j] = agg[row,j] / (||agg[row,:]|| + 1e-9); one wave/row.
__global__ void l2norm_kernel(const float* __restrict__ agg, int d,
                              void* __restrict__ out, size_t elem_off, int n,
                              const int* __restrict__ dflag) {
    int row = blockIdx.x * (blockDim.x >> 6) + (threadIdx.x >> 6);
    if (row >= n) return;
    int isb  = *dflag;
    int lane = threadIdx.x & 63;
    const float2* a2 = (const float2*)(agg + (size_t)row * d);
    float ss = 0.f;
    for (int j = 2 * lane; j < d; j += 128) {
        float2 x = a2[j >> 1];
        ss += x.x * x.x + x.y * x.y;
    }
    #pragma unroll
    for (int off = 32; off > 0; off >>= 1) ss += __shfl_down(ss, off);
    ss = __shfl(ss, 0);
    float inv = 1.0f / (sqrtf(ss) + 1e-9f);
    size_t bbase = elem_off + (size_t)row * d;
    if (isb) {
        unsigned* o = (unsigned*)((bf16*)out + bbase);
        for (int j = 2 * lane; j < d; j += 128) {
            float2 x = a2[j >> 1];
            o[j >> 1] = f2b(x.x * inv) | (f2b(x.y * inv) << 16);
        }
    } else {
        float2* o = (float2*)((float*)out + bbase);
        for (int j = 2 * lane; j < d; j += 128) {
            float2 x = a2[j >> 1];
            o[j >> 1] = make_float2(x.x * inv, x.y * inv);
        }
    }
}

static inline int spmm_grid(int nE) { return (nE + 3) / 4; }
static inline int row_grid(int n)   { return (n + 3) / 4; }

// Fused per-phase CSR build for two matrices A,B sharing one cursor block.
static void build2(hipStream_t stream,
                   const int* rowsA, const int* colsA, const void* valsA, int nA, int nEA,
                   const int* rowsB, const int* colsB, const void* valsB, int nB, int nEB,
                   int* rpA, int* rpB, int* curAB, int2* pairsA, int2* pairsB,
                   const int* dflag) {
    int nE = nEA + nEB;
    hipMemsetAsync(curAB, 0, (size_t)(nA + nB) * 4, stream);
    hist2_kernel<<<(nE + 255) / 256, 256, 0, stream>>>(rowsA, nEA, rowsB, nEB, nA, curAB);
    scan2_kernel<<<1, 1024, 0, stream>>>(curAB, rpA, nA, curAB + nA, rpB, nB);
    copy2_kernel<<<(nA + nB + 255) / 256, 256, 0, stream>>>(rpA, rpB, nA, nB, curAB);
    scatter2_kernel<<<(nE + 255) / 256, 256, 0, stream>>>(
        rowsA, colsA, valsA, nEA, rowsB, colsB, valsB, nEB, nA, curAB, pairsA, pairsB, dflag);
}

extern "C" void kernel_launch(void* const* d_in, const int* in_sizes, int n_in,
                              void* d_out, int out_size, void* d_ws, size_t ws_size,
                              hipStream_t stream) {
    const void* f1   = d_in[0];
    const void* f2   = d_in[1];
    const void* f3   = d_in[2];
    const void* wemb = d_in[3];
    const int*  a11r = (const int*)d_in[4];
    const int*  a11c = (const int*)d_in[5];
    const void* a11v = d_in[6];
    const int*  a22r = (const int*)d_in[7];
    const int*  a22c = (const int*)d_in[8];
    const void* a22v = d_in[9];
    const int*  a33r = (const int*)d_in[10];
    const int*  a33c = (const int*)d_in[11];
    const void* a33v = d_in[12];
    const int*  a01r = (const int*)d_in[13];
    const int*  a01c = (const int*)d_in[14];
    const void* a01v = d_in[15];
    const int*  a02r = (const int*)d_in[16];
    const int*  a02c = (const int*)d_in[17];
    const void* a02v = d_in[18];
    const int*  a03r = (const int*)d_in[19];
    const int*  a03c = (const int*)d_in[20];
    const void* a03v = d_in[21];
    const void* W3   = d_in[22];
    const void* b3   = d_in[23];
    const void* W1_2 = d_in[24];
    const void* b1_2 = d_in[25];
    const void* W2_2 = d_in[26];
    const void* b2_2 = d_in[27];
    const void* W3_2 = d_in[28];
    const void* b3_2 = d_in[29];

    int*   dflag = (int*)d_ws;
    float* base  = (float*)d_ws + 16;       // dense buffers start 64 B in
    float* S0   = base;                     // 20000*128
    float* S1   = base + 2560000;           // 20000*128
    float* AGG1 = S1;                       // 10000*128 (S1 dead when used)
    float* E0   = base;                     // 10000*128
    float* E1   = base + 1280000;           // 10000*128
    float* AGG2 = base + 1280000;           // 10000*428 (E1 dead when used)
    float* P3a  = base;                     // 60*128
    float* P3b  = base + 7680;              // 60*128
    float* AGG3 = base + 15360;             // 10000*128

    // CSR region after dense peak; per-phase layout (int counts all even ->
    // pairs stay 8B-aligned): [rpA(nA+1) | rpB(nB+1) | curAB(nA+nB) | pairsA | pairsB]
    int* I = (int*)(base + 5560000);
    const size_t WS_NEEDED = 64 + 22240000ull + 240008ull + 4960000ull; // phase-1 peak ~27.44 MB

    const size_t OUT1_OFF = 0;
    const size_t OUT2_OFF = (size_t)N_DOC * DD;                       // 1,280,000
    const size_t OUT3_OFF = OUT2_OFF + (size_t)N_DOC * (DD + D_WEMB); // 5,560,000

    dim3 blk(256);
    detect_kernel<<<1, 256, 0, stream>>>((const unsigned*)f1, dflag);

    if (ws_size >= WS_NEEDED) {
        // ================= CSR gather path =================
        // ---------------- type 1 (words): A=A11 (20000), B=A01 (10000) ----------------
        {
            int* rpA = I; int* rpB = rpA + (N_WORD + 1); int* cur = rpB + (N_DOC + 1);
            int2* pA = (int2*)(cur + N_WORD + N_DOC); int2* pB = pA + E11;
            build2(stream, a11r, a11c, a11v, N_WORD, E11,
                   a01r, a01c, a01v, N_DOC, E01, rpA, rpB, cur, pA, pB, dflag);
            spmm_gather<false, 128><<<row_grid(N_WORD), blk, 0, stream>>>(
                rpA, pA, f1, DD, 1, S0, DD, 0, N_WORD, dflag);        // S0 = A11@f1
            gemm_tile<true><<<dim3((N_WORD + 63) / 64, 4), 256, 0, stream>>>(
                S0, W1_2, b1_2, S1, N_WORD, dflag);                   // S1 = relu(S0)@W+b
            spmm_gather<false, 128><<<row_grid(N_WORD), blk, 0, stream>>>(
                rpA, pA, S1, DD, 0, S0, DD, 0, N_WORD, dflag);        // S0 = A11@S1
            spmm_gather<true, 128><<<row_grid(N_DOC), blk, 0, stream>>>(
                rpB, pB, S0, DD, 0, AGG1, DD, 0, N_DOC, dflag);       // AGG1 = A01@relu(S0)
            l2norm_kernel<<<row_grid(N_DOC), blk, 0, stream>>>(
                AGG1, DD, d_out, OUT1_OFF, N_DOC, dflag);
        }
        // ---------------- type 2 (entities): A=A22 (10000), B=A02 (10000) ----------------
        {
            int* rpA = I; int* rpB = rpA + (N_ENT + 1); int* cur = rpB + (N_DOC + 1);
            int2* pA = (int2*)(cur + N_ENT + N_DOC); int2* pB = pA + E22;
            build2(stream, a22r, a22c, a22v, N_ENT, E22,
                   a02r, a02c, a02v, N_DOC, E02, rpA, rpB, cur, pA, pB, dflag);
            spmm_gather<false, 128><<<row_grid(N_ENT), blk, 0, stream>>>(
                rpA, pA, f2, DD, 1, E0, DD, 0, N_ENT, dflag);         // E0 = A22@f2
            gemm_tile<true><<<dim3((N_ENT + 63) / 64, 4), 256, 0, stream>>>(
                E0, W2_2, b2_2, E1, N_ENT, dflag);                    // E1 = relu(E0)@W+b
            spmm_gather<false, 128><<<row_grid(N_ENT), blk, 0, stream>>>(
                rpA, pA, E1, DD, 0, E0, DD, 0, N_ENT, dflag);         // E0 = A22@E1
            spmm_gather<true, 128><<<row_grid(N_DOC), blk, 0, stream>>>(
                rpB, pB, E0, DD, 0, AGG2, DD + D_WEMB, 0, N_DOC, dflag);
            spmm_gather<false, 300><<<row_grid(N_DOC), blk, 0, stream>>>(
                rpB, pB, wemb, D_WEMB, 1, AGG2, DD + D_WEMB, DD, N_DOC, dflag);
            l2norm_kernel<<<row_grid(N_DOC), blk, 0, stream>>>(
                AGG2, DD + D_WEMB, d_out, OUT2_OFF, N_DOC, dflag);
        }
        // ---------------- type 3 (POS): A=A33 (60), B=A03 (10000) ----------------
        {
            int* rpA = I; int* rpB = rpA + (N_POS + 1); int* cur = rpB + (N_DOC + 1);
            int2* pA = (int2*)(cur + N_POS + N_DOC); int2* pB = pA + E33;
            build2(stream, a33r, a33c, a33v, N_POS, E33,
                   a03r, a03c, a03v, N_DOC, E03, rpA, rpB, cur, pA, pB, dflag);
            rowpar_gemm<false, 60><<<N_POS, 128, 0, stream>>>(
                f3, 1, W3, b3, P3a, dflag);                           // P3a = f3@W3+b3
            spmm_gather<false, 128><<<row_grid(N_POS), blk, 0, stream>>>(
                rpA, pA, P3a, DD, 0, P3b, DD, 0, N_POS, dflag);       // P3b = A33@P3a
            rowpar_gemm<true, 128><<<N_POS, 128, 0, stream>>>(
                P3b, 0, W3_2, b3_2, P3a, dflag);                      // P3a = relu(P3b)@W+b
            spmm_gather<false, 128><<<row_grid(N_POS), blk, 0, stream>>>(
                rpA, pA, P3a, DD, 0, P3b, DD, 0, N_POS, dflag);       // P3b = A33@P3a
            spmm_gather<true, 128><<<row_grid(N_DOC), blk, 0, stream>>>(
                rpB, pB, P3b, DD, 0, AGG3, DD, 0, N_DOC, dflag);      // AGG3 = A03@relu(P3b)
            l2norm_kernel<<<row_grid(N_DOC), blk, 0, stream>>>(
                AGG3, DD, d_out, OUT3_OFF, N_DOC, dflag);
        }
    } else {
        // ================= fallback: atomic-scatter path =================
        hipMemsetAsync(S0, 0, (size_t)N_WORD * DD * 4, stream);
        spmm_kernel<false><<<spmm_grid(E11), blk, 0, stream>>>(
            a11r, a11c, a11v, f1, DD, 1, S0, DD, 0, DD, E11, dflag);
        gemm128_kernel<true><<<(N_WORD + 63) / 64, 256, 0, stream>>>(
            S0, W1_2, b1_2, S1, N_WORD, dflag);
        hipMemsetAsync(S0, 0, (size_t)N_WORD * DD * 4, stream);
        spmm_kernel<false><<<spmm_grid(E11), blk, 0, stream>>>(
            a11r, a11c, a11v, S1, DD, 0, S0, DD, 0, DD, E11, dflag);
        hipMemsetAsync(AGG1, 0, (size_t)N_DOC * DD * 4, stream);
        spmm_kernel<true><<<spmm_grid(E01), blk, 0, stream>>>(
            a01r, a01c, a01v, S0, DD, 0, AGG1, DD, 0, DD, E01, dflag);
        l2norm_kernel<<<row_grid(N_DOC), blk, 0, stream>>>(
            AGG1, DD, d_out, OUT1_OFF, N_DOC, dflag);

        hipMemsetAsync(E0, 0, (size_t)N_ENT * DD * 4, stream);
        spmm_kernel<false><<<spmm_grid(E22), blk, 0, stream>>>(
            a22r, a22c, a22v, f2, DD, 1, E0, DD, 0, DD, E22, dflag);
        gemm128_kernel<true><<<(N_ENT + 63) / 64, 256, 0, stream>>>(
            E0, W2_2, b2_2, E1, N_ENT, dflag);
        hipMemsetAsync(E0, 0, (size_t)N_ENT * DD * 4, stream);
        spmm_kernel<false><<<spmm_grid(E22), blk, 0, stream>>>(
            a22r, a22c, a22v, E1, DD, 0, E0, DD, 0, DD, E22, dflag);
        hipMemsetAsync(AGG2, 0, (size_t)N_DOC * (DD + D_WEMB) * 4, stream);
        spmm_kernel<true><<<spmm_grid(E02), blk, 0, stream>>>(
            a02r, a02c, a02v, E0, DD, 0, AGG2, DD + D_WEMB, 0, DD, E02, dflag);
        spmm_kernel<false><<<spmm_grid(E02), blk, 0, stream>>>(
            a02r, a02c, a02v, wemb, D_WEMB, 1, AGG2, DD + D_WEMB, DD, D_WEMB, E02, dflag);
        l2norm_kernel<<<row_grid(N_DOC), blk, 0, stream>>>(
            AGG2, DD + D_WEMB, d_out, OUT2_OFF, N_DOC, dflag);

        gemm_kernel<false, 60><<<1, 128, 0, stream>>>(f3, 1, W3, b3, P3a, N_POS, dflag);
        hipMemsetAsync(P3b, 0, (size_t)N_POS * DD * 4, stream);
        spmm_kernel<false><<<spmm_grid(E33), blk, 0, stream>>>(
            a33r, a33c, a33v, P3a, DD, 0, P3b, DD, 0, DD, E33, dflag);
        gemm128_kernel<true><<<1, 256, 0, stream>>>(
            P3b, W3_2, b3_2, P3a, N_POS, dflag);
        hipMemsetAsync(P3b, 0, (size_t)N_POS * DD * 4, stream);
        spmm_kernel<false><<<spmm_grid(E33), blk, 0, stream>>>(
            a33r, a33c, a33v, P3a, DD, 0, P3b, DD, 0, DD, E33, dflag);
        hipMemsetAsync(AGG3, 0, (size_t)N_DOC * DD * 4, stream);
        spmm_kernel<true><<<spmm_grid(E03), blk, 0, stream>>>(
            a03r, a03c, a03v, P3b, DD, 0, AGG3, DD, 0, DD, E03, dflag);
        l2norm_kernel<<<row_grid(N_DOC), blk, 0, stream>>>(
            AGG3, DD, d_out, OUT3_OFF, N_DOC, dflag);
    }
}

// Round 9
// 630.177 us; speedup vs baseline: 4.3292x; 1.0092x over previous
//
#include <hip/hip_runtime.h>
#include <hip/hip_bf16.h>

typedef __hip_bfloat16 bf16;

#define N_DOC   10000
#define N_WORD  20000
#define N_ENT   10000
#define N_POS   60
#define DD      128
#define D_WEMB  300
#define E11     320000
#define E22     160000
#define E33     3600
#define E01     300000
#define E02     100000
#define E03     150000

// Runtime dtype flag (ws[0]): 1 if float inputs are packed bf16, 0 if fp32.
// When flag==1, ws intermediates are ALSO stored bf16 (fp32 accumulate, bf16 store).
__device__ __forceinline__ float loadf(const void* p, size_t i, int isb) {
    return isb ? __bfloat162float(((const bf16*)p)[i])
               : ((const float*)p)[i];
}
__device__ __forceinline__ float b2f(unsigned u16) {
    union { unsigned v; float f; } x; x.v = u16 << 16; return x.f;
}
__device__ __forceinline__ unsigned f2b(float f) {
    bf16 h = __float2bfloat16(f);
    union { bf16 h; unsigned short u; } x; x.h = h; return (unsigned)x.u;
}
__device__ __forceinline__ void storef(void* p, size_t i, int asb, float v) {
    if (asb) ((unsigned short*)p)[i] = (unsigned short)f2b(v);
    else     ((float*)p)[i] = v;
}

// Detect input dtype from a randn fp32-or-bf16 buffer (see R2 notes).
__global__ void detect_kernel(const unsigned* __restrict__ probe, int* __restrict__ flag) {
    __shared__ int cnt;
    if (threadIdx.x == 0) cnt = 0;
    __syncthreads();
    int insane = 0;
    for (int i = threadIdx.x; i < 1024; i += 256) {
        float x = __uint_as_float(probe[i]);
        float a = fabsf(x);
        if (!(a > 1e-10f && a < 1e10f)) insane++;
    }
    atomicAdd(&cnt, insane);
    __syncthreads();
    if (threadIdx.x == 0) *flag = (cnt > 512) ? 1 : 0;
}

// ======================= fused 2-matrix CSR build =======================
__global__ void hist2_kernel(const int* __restrict__ rowsA, int nEA,
                             const int* __restrict__ rowsB, int nEB,
                             int nA, int* __restrict__ cnt) {
    int i = blockIdx.x * blockDim.x + threadIdx.x;
    if (i < nEA) atomicAdd(cnt + rowsA[i], 1);
    else if (i < nEA + nEB) atomicAdd(cnt + nA + rowsB[i - nEA], 1);
}

// Exclusive scan (1024 threads, wave shfl-scan + cross-wave LDS).
__device__ void scan_ex(const int* __restrict__ cnt, int* __restrict__ rp, int n) {
    __shared__ int wsum[16];
    __shared__ int carry;
    int t = threadIdx.x, lane = t & 63, w = t >> 6;
    if (t == 0) carry = 0;
    __syncthreads();
    for (int base = 0; base < n; base += 1024) {
        int i = base + t;
        int x = (i < n) ? cnt[i] : 0;
        int s = x;
        #pragma unroll
        for (int off = 1; off < 64; off <<= 1) {
            int y = __shfl_up(s, off);
            if (lane >= off) s += y;
        }
        if (lane == 63) wsum[w] = s;
        __syncthreads();
        if (w == 0) {
            int v = (lane < 16) ? wsum[lane] : 0;
            #pragma unroll
            for (int off = 1; off < 16; off <<= 1) {
                int y = __shfl_up(v, off);
                if (lane >= off) v += y;
            }
            if (lane < 16) wsum[lane] = v;
        }
        __syncthreads();
        int woff = (w > 0) ? wsum[w - 1] : 0;
        if (i < n) rp[i] = carry + woff + s - x;
        __syncthreads();
        if (t == 0) carry += wsum[15];
        __syncthreads();
    }
    if (t == 0) rp[n] = carry;
}

__global__ __launch_bounds__(1024) void scan2_kernel(
        const int* __restrict__ cntA, int* __restrict__ rpA, int nA,
        const int* __restrict__ cntB, int* __restrict__ rpB, int nB) {
    scan_ex(cntA, rpA, nA);
    __syncthreads();
    scan_ex(cntB, rpB, nB);
}

__global__ void copy2_kernel(const int* __restrict__ rpA, const int* __restrict__ rpB,
                             int nA, int nB, int* __restrict__ cur) {
    int i = blockIdx.x * blockDim.x + threadIdx.x;
    if (i < nA) cur[i] = rpA[i];
    else if (i < nA + nB) cur[i] = rpB[i - nA];
}

__global__ void scatter2_kernel(const int* __restrict__ rowsA, const int* __restrict__ colsA,
                                const void* __restrict__ valsA, int nEA,
                                const int* __restrict__ rowsB, const int* __restrict__ colsB,
                                const void* __restrict__ valsB, int nEB,
                                int nA, int* __restrict__ cur,
                                int2* __restrict__ pairsA, int2* __restrict__ pairsB,
                                const int* __restrict__ dflag) {
    int i = blockIdx.x * blockDim.x + threadIdx.x;
    int isb = *dflag;
    if (i < nEA) {
        int p = atomicAdd(cur + rowsA[i], 1);
        pairsA[p] = make_int2(colsA[i], __float_as_int(loadf(valsA, i, isb)));
    } else if (i < nEA + nEB) {
        int k = i - nEA;
        int p = atomicAdd(cur + nA + rowsB[k], 1);
        pairsB[p] = make_int2(colsB[k], __float_as_int(loadf(valsB, k, isb)));
    }
}

// ======================= gather SpMM (no atomics) =======================
// dst[row, doff+0..D) = sum_e vals[e] * act(src[cols[e], 0..D)); one wave/row.
// 2-edge unroll, dual accumulators. src/dst dtype follow *dflag when flagged.
template<bool RELU, int D>
__global__ void spmm_gather(const int* __restrict__ rowptr, const int2* __restrict__ pairs,
                            const void* __restrict__ src, int sstride, int src_flagged,
                            void* __restrict__ dst, int dstride, int doff, int dst_flagged,
                            int n, const int* __restrict__ dflag) {
    constexpr int PAIRS = D / 2;
    constexpr int NS = (PAIRS + 63) / 64;
    int row = blockIdx.x * (blockDim.x >> 6) + (threadIdx.x >> 6);
    if (row >= n) return;
    int isb  = *dflag;
    int sisb = src_flagged ? isb : 0;
    int disb = dst_flagged ? isb : 0;
    int lane = threadIdx.x & 63;
    int e0 = rowptr[row], e1 = rowptr[row + 1];
    float2 acc[NS], acc2[NS];
    #pragma unroll
    for (int s = 0; s < NS; ++s) { acc[s] = make_float2(0.f, 0.f); acc2[s] = make_float2(0.f, 0.f); }
    if (sisb) {
        int e = e0;
        for (; e + 2 <= e1; e += 2) {
            int2 p0 = pairs[e], p1 = pairs[e + 1];
            float v0 = __int_as_float(p0.y), v1 = __int_as_float(p1.y);
            const unsigned* s0 = (const unsigned*)((const bf16*)src + (size_t)p0.x * sstride);
            const unsigned* s1 = (const unsigned*)((const bf16*)src + (size_t)p1.x * sstride);
            #pragma unroll
            for (int s = 0; s < NS; ++s) {
                int pi = lane + 64 * s;
                if (pi < PAIRS) {
                    unsigned u0 = s0[pi], u1 = s1[pi];
                    float a0 = b2f(u0 & 0xffffu), a1 = b2f(u0 >> 16);
                    float c0 = b2f(u1 & 0xffffu), c1 = b2f(u1 >> 16);
                    if (RELU) { a0 = fmaxf(a0, 0.f); a1 = fmaxf(a1, 0.f);
                                c0 = fmaxf(c0, 0.f); c1 = fmaxf(c1, 0.f); }
                    acc[s].x  = fmaf(v0, a0, acc[s].x);
                    acc[s].y  = fmaf(v0, a1, acc[s].y);
                    acc2[s].x = fmaf(v1, c0, acc2[s].x);
                    acc2[s].y = fmaf(v1, c1, acc2[s].y);
                }
            }
        }
        if (e < e1) {
            int2 p = pairs[e];
            float v = __int_as_float(p.y);
            const unsigned* sp = (const unsigned*)((const bf16*)src + (size_t)p.x * sstride);
            #pragma unroll
            for (int s = 0; s < NS; ++s) {
                int pi = lane + 64 * s;
                if (pi < PAIRS) {
                    unsigned u = sp[pi];
                    float x0 = b2f(u & 0xffffu), x1 = b2f(u >> 16);
                    if (RELU) { x0 = fmaxf(x0, 0.f); x1 = fmaxf(x1, 0.f); }
                    acc[s].x = fmaf(v, x0, acc[s].x);
                    acc[s].y = fmaf(v, x1, acc[s].y);
                }
            }
        }
    } else {
        int e = e0;
        for (; e + 2 <= e1; e += 2) {
            int2 p0 = pairs[e], p1 = pairs[e + 1];
            float v0 = __int_as_float(p0.y), v1 = __int_as_float(p1.y);
            const float2* s0 = (const float2*)((const float*)src + (size_t)p0.x * sstride);
            const float2* s1 = (const float2*)((const float*)src + (size_t)p1.x * sstride);
            #pragma unroll
            for (int s = 0; s < NS; ++s) {
                int pi = lane + 64 * s;
                if (pi < PAIRS) {
                    float2 x = s0[pi], y = s1[pi];
                    if (RELU) { x.x = fmaxf(x.x, 0.f); x.y = fmaxf(x.y, 0.f);
                                y.x = fmaxf(y.x, 0.f); y.y = fmaxf(y.y, 0.f); }
                    acc[s].x  = fmaf(v0, x.x, acc[s].x);
                    acc[s].y  = fmaf(v0, x.y, acc[s].y);
                    acc2[s].x = fmaf(v1, y.x, acc2[s].x);
                    acc2[s].y = fmaf(v1, y.y, acc2[s].y);
                }
            }
        }
        if (e < e1) {
            int2 p = pairs[e];
            float v = __int_as_float(p.y);
            const float2* sp = (const float2*)((const float*)src + (size_t)p.x * sstride);
            #pragma unroll
            for (int s = 0; s < NS; ++s) {
                int pi = lane + 64 * s;
                if (pi < PAIRS) {
                    float2 x = sp[pi];
                    if (RELU) { x.x = fmaxf(x.x, 0.f); x.y = fmaxf(x.y, 0.f); }
                    acc[s].x = fmaf(v, x.x, acc[s].x);
                    acc[s].y = fmaf(v, x.y, acc[s].y);
                }
            }
        }
    }
    if (disb) {
        unsigned* dp = (unsigned*)((bf16*)dst + (size_t)row * dstride + doff);  // even elem idx -> 4B aligned
        #pragma unroll
        for (int s = 0; s < NS; ++s) {
            int pi = lane + 64 * s;
            if (pi < PAIRS)
                dp[pi] = f2b(acc[s].x + acc2[s].x) | (f2b(acc[s].y + acc2[s].y) << 16);
        }
    } else {
        float2* dp = (float2*)((float*)dst + (size_t)row * dstride + doff);
        #pragma unroll
        for (int s = 0; s < NS; ++s) {
            int pi = lane + 64 * s;
            if (pi < PAIRS) dp[pi] = make_float2(acc[s].x + acc2[s].x, acc[s].y + acc2[s].y);
        }
    }
}

// ======================= atomic SpMM (ws_size fallback only) =======================
template<bool RELU>
__global__ void spmm_kernel(const int* __restrict__ rows, const int* __restrict__ cols,
                            const void* __restrict__ vals,
                            const void* __restrict__ src, int sstride, int src_flagged,
                            float* __restrict__ dst, int dstride, int doff,
                            int d, int nE, const int* __restrict__ dflag) {
    int e = blockIdx.x * (blockDim.x >> 6) + (threadIdx.x >> 6);
    if (e >= nE) return;
    int isb  = *dflag;
    int sisb = src_flagged ? isb : 0;
    int lane = threadIdx.x & 63;
    int r = rows[e];
    int c = cols[e];
    float v = loadf(vals, e, isb);
    size_t sbase = (size_t)c * sstride;
    float* dp = dst + (size_t)r * dstride + doff;
    if (sisb) {
        const unsigned* sp = (const unsigned*)((const bf16*)src + sbase);
        for (int j = 2 * lane; j < d; j += 128) {
            unsigned u = sp[j >> 1];
            float x0 = b2f(u & 0xffffu);
            float x1 = b2f(u >> 16);
            if (RELU) { x0 = fmaxf(x0, 0.f); x1 = fmaxf(x1, 0.f); }
            atomicAdd(dp + j,     v * x0);
            atomicAdd(dp + j + 1, v * x1);
        }
    } else {
        const float2* sp = (const float2*)((const float*)src + sbase);
        for (int j = 2 * lane; j < d; j += 128) {
            float2 x = sp[j >> 1];
            if (RELU) { x.x = fmaxf(x.x, 0.f); x.y = fmaxf(x.y, 0.f); }
            atomicAdd(dp + j,     v * x.x);
            atomicAdd(dp + j + 1, v * x.y);
        }
    }
}

// ======================= dense GEMMs =======================
// out[n x 128] = act(X[n x 128]) @ W[128 x 128] + b.
// 32-column W tile in 16 KB LDS; 2D grid (row tiles x 4 col tiles).
// X and out follow *dflag (bf16 ws intermediates when inputs are bf16).
template<bool RELU>
__global__ __launch_bounds__(256) void gemm_tile(
        const void* __restrict__ X, const void* __restrict__ W,
        const void* __restrict__ b, void* __restrict__ out, int n,
        const int* __restrict__ dflag) {
    __shared__ float Wl[128 * 32];
    int isb = *dflag;
    int tid = threadIdx.x;
    int jc = blockIdx.y * 32;
    if (isb) {
        const uint2* Wg = (const uint2*)W;            // 4 bf16 per uint2, row = 32 uint2
        float4* Wl4 = (float4*)Wl;
        for (int vidx = tid; vidx < 1024; vidx += 256) {
            int k = vidx >> 3, jl4 = vidx & 7;
            uint2 u = Wg[k * 32 + (jc >> 2) + jl4];
            float4 vv;
            vv.x = b2f(u.x & 0xffffu);
            vv.y = b2f(u.x >> 16);
            vv.z = b2f(u.y & 0xffffu);
            vv.w = b2f(u.y >> 16);
            Wl4[vidx] = vv;
        }
    } else {
        const float4* Wg = (const float4*)W;          // row = 32 float4
        float4* Wl4 = (float4*)Wl;
        for (int vidx = tid; vidx < 1024; vidx += 256) {
            int k = vidx >> 3, jl4 = vidx & 7;
            Wl4[vidx] = Wg[k * 32 + (jc >> 2) + jl4];
        }
    }
    __syncthreads();
    int j = tid & 31;
    int g = tid >> 5;
    float bj = loadf(b, jc + j, isb);
    int i0 = blockIdx.x * 64 + g * 8;
    float a[8];
    #pragma unroll
    for (int r = 0; r < 8; ++r) a[r] = bj;
    if (isb) {
        const uint2* xp = (const uint2*)((const bf16*)X + (size_t)i0 * 128);  // row r: xp + r*32
        #pragma unroll 2
        for (int k4 = 0; k4 < 32; ++k4) {
            float w0 = Wl[(4 * k4 + 0) * 32 + j];
            float w1 = Wl[(4 * k4 + 1) * 32 + j];
            float w2 = Wl[(4 * k4 + 2) * 32 + j];
            float w3 = Wl[(4 * k4 + 3) * 32 + j];
            #pragma unroll
            for (int r = 0; r < 8; ++r) {
                uint2 u = xp[r * 32 + k4];
                float vx = b2f(u.x & 0xffffu), vy = b2f(u.x >> 16);
                float vz = b2f(u.y & 0xffffu), vw = b2f(u.y >> 16);
                if (RELU) {
                    vx = fmaxf(vx, 0.f); vy = fmaxf(vy, 0.f);
                    vz = fmaxf(vz, 0.f); vw = fmaxf(vw, 0.f);
                }
                a[r] = fmaf(vw, w3, fmaf(vz, w2, fmaf(vy, w1, fmaf(vx, w0, a[r]))));
            }
        }
    } else {
        const float4* xp = (const float4*)((const float*)X + (size_t)i0 * 128);
        #pragma unroll 2
        for (int k4 = 0; k4 < 32; ++k4) {
            float w0 = Wl[(4 * k4 + 0) * 32 + j];
            float w1 = Wl[(4 * k4 + 1) * 32 + j];
            float w2 = Wl[(4 * k4 + 2) * 32 + j];
            float w3 = Wl[(4 * k4 + 3) * 32 + j];
            #pragma unroll
            for (int r = 0; r < 8; ++r) {
                float4 v = xp[r * 32 + k4];
                if (RELU) {
                    v.x = fmaxf(v.x, 0.f); v.y = fmaxf(v.y, 0.f);
                    v.z = fmaxf(v.z, 0.f); v.w = fmaxf(v.w, 0.f);
                }
                a[r] = fmaf(v.w, w3, fmaf(v.z, w2, fmaf(v.y, w1, fmaf(v.x, w0, a[r]))));
            }
        }
    }
    #pragma unroll
    for (int r = 0; r < 8; ++r) {
        int i = i0 + r;
        if (i < n) storef(out, (size_t)i * 128 + jc + j, isb, a[r]);
    }
}

// Legacy big-LDS GEMM (fallback path only; fp32 ws).
template<bool RELU>
__global__ __launch_bounds__(256) void gemm128_kernel(
        const float* __restrict__ X, const void* __restrict__ W,
        const void* __restrict__ b, float* __restrict__ out, int n,
        const int* __restrict__ dflag) {
    __shared__ float Wl[128 * 128];
    int isb = *dflag;
    int tid = threadIdx.x;
    if (isb) {
        const uint2* Wg = (const uint2*)W;
        float4* Wl4 = (float4*)Wl;
        for (int idx = tid; idx < 4096; idx += 256) {
            uint2 u = Wg[idx];
            float4 vv;
            vv.x = b2f(u.x & 0xffffu);
            vv.y = b2f(u.x >> 16);
            vv.z = b2f(u.y & 0xffffu);
            vv.w = b2f(u.y >> 16);
            Wl4[idx] = vv;
        }
    } else {
        const float4* Wg = (const float4*)W;
        float4* Wl4 = (float4*)Wl;
        for (int idx = tid; idx < 4096; idx += 256) Wl4[idx] = Wg[idx];
    }
    __syncthreads();
    int j = tid & 127;
    int h = tid >> 7;
    float bj = loadf(b, j, isb);
    int row0 = blockIdx.x * 64 + h * 32;
    for (int q = 0; q < 8; ++q) {
        int gi = row0 + q * 4;
        if (gi >= n) break;
        const float4* x0 = (const float4*)(X + (size_t)gi * 128);
        const float4* x1 = x0 + 32;
        const float4* x2 = x1 + 32;
        const float4* x3 = x2 + 32;
        float a0 = bj, a1 = bj, a2 = bj, a3 = bj;
        #pragma unroll 4
        for (int k4 = 0; k4 < 32; ++k4) {
            float4 v0 = x0[k4], v1 = x1[k4], v2 = x2[k4], v3 = x3[k4];
            if (RELU) {
                v0.x = fmaxf(v0.x, 0.f); v0.y = fmaxf(v0.y, 0.f); v0.z = fmaxf(v0.z, 0.f); v0.w = fmaxf(v0.w, 0.f);
                v1.x = fmaxf(v1.x, 0.f); v1.y = fmaxf(v1.y, 0.f); v1.z = fmaxf(v1.z, 0.f); v1.w = fmaxf(v1.w, 0.f);
                v2.x = fmaxf(v2.x, 0.f); v2.y = fmaxf(v2.y, 0.f); v2.z = fmaxf(v2.z, 0.f); v2.w = fmaxf(v2.w, 0.f);
                v3.x = fmaxf(v3.x, 0.f); v3.y = fmaxf(v3.y, 0.f); v3.z = fmaxf(v3.z, 0.f); v3.w = fmaxf(v3.w, 0.f);
            }
            float w0 = Wl[(4 * k4 + 0) * 128 + j];
            float w1 = Wl[(4 * k4 + 1) * 128 + j];
            float w2 = Wl[(4 * k4 + 2) * 128 + j];
            float w3 = Wl[(4 * k4 + 3) * 128 + j];
            a0 = fmaf(v0.w, w3, fmaf(v0.z, w2, fmaf(v0.y, w1, fmaf(v0.x, w0, a0))));
            a1 = fmaf(v1.w, w3, fmaf(v1.z, w2, fmaf(v1.y, w1, fmaf(v1.x, w0, a1))));
            a2 = fmaf(v2.w, w3, fmaf(v2.z, w2, fmaf(v2.y, w1, fmaf(v2.x, w0, a2))));
            a3 = fmaf(v3.w, w3, fmaf(v3.z, w2, fmaf(v3.y, w1, fmaf(v3.x, w0, a3))));
        }
        float* o = out + (size_t)gi * 128 + j;
        o[0] = a0; o[128] = a1; o[256] = a2; o[384] = a3;
    }
}

// Row-parallel tiny GEMM (type-3, n=60): one block per row, 128 threads.
// X (when x_flagged) and out follow *dflag.
template<bool RELU, int K>
__global__ void rowpar_gemm(const void* __restrict__ X, int x_flagged,
                            const void* __restrict__ W, const void* __restrict__ b,
                            void* __restrict__ out, int out_flagged,
                            const int* __restrict__ dflag) {
    __shared__ float xr[K];
    int isb  = *dflag;
    int xisb = x_flagged ? isb : 0;
    int oisb = out_flagged ? isb : 0;
    int row = blockIdx.x;
    int j = threadIdx.x;
    if (j < K) {
        float x = loadf(X, (size_t)row * K + j, xisb);
        if (RELU) x = fmaxf(x, 0.f);
        xr[j] = x;
    }
    __syncthreads();
    float acc = loadf(b, j, isb);
    #pragma unroll 8
    for (int k = 0; k < K; ++k)
        acc = fmaf(xr[k], loadf(W, (size_t)k * 128 + j, isb), acc);
    storef(out, (size_t)row * 128 + j, oisb, acc);
}

// Generic small GEMM (fallback path only).
template<bool RELU, int K>
__global__ void gemm_kernel(const void* __restrict__ X, int x_flagged,
                            const void* __restrict__ W,
                            const void* __restrict__ b,
                            float* __restrict__ out, int n,
                            const int* __restrict__ dflag) {
    __shared__ float Wl[K * 128];
    int isb  = *dflag;
    int xisb = x_flagged ? isb : 0;
    int j = threadIdx.x;
    for (int idx = j; idx < K * 128; idx += 128)
        Wl[idx] = loadf(W, idx, isb);
    __syncthreads();
    float bj = loadf(b, j, isb);
    int row0 = blockIdx.x * 64;
    for (int i0 = 0; i0 < 64; i0 += 4) {
        int i = row0 + i0;
        if (i >= n) break;
        size_t r0 = (size_t)i * K;
        float a0 = bj, a1 = bj, a2 = bj, a3 = bj;
        for (int k = 0; k < K; ++k) {
            float w = Wl[k * 128 + j];
            float v0 = loadf(X, r0 + k, xisb);
            float v1 = loadf(X, r0 + K + k, xisb);
            float v2 = loadf(X, r0 + 2 * K + k, xisb);
            float v3 = loadf(X, r0 + 3 * K + k, xisb);
            if (RELU) {
                v0 = fmaxf(v0, 0.f); v1 = fmaxf(v1, 0.f);
                v2 = fmaxf(v2, 0.f); v3 = fmaxf(v3, 0.f);
            }
            a0 = fmaf(v0, w, a0);
            a1 = fmaf(v1, w, a1);
            a2 = fmaf(v2, w, a2);
            a3 = fmaf(v3, w, a3);
        }
        float* o = out + (size_t)i * 128 + j;
        o[0] = a0; o[128] = a1; o[256] = a2; o[384] = a3;
    }
}

// out[elem_off + row*d + j] = agg[row,j] / (||agg[row,:]|| + 1e-9); one wave/row.
__global__ void l2norm_kernel(const float* __restrict__ agg, int d,
                              void* __restrict__ out, size_t elem_off, int n,
                              const int* __restrict__ dflag) {
    int row = blockIdx.x * (blockDim.x >> 6) + (threadIdx.x >> 6);
    if (row >= n) return;
    int isb  = *dflag;
    int lane = threadIdx.x & 63;
    const float2* a2 = (const float2*)(agg + (size_t)row * d);
    float ss = 0.f;
    for (int j = 2 * lane; j < d; j += 128) {
        float2 x = a2[j >> 1];
        ss += x.x * x.x + x.y * x.y;
    }
    #pragma unroll
    for (int off = 32; off > 0; off >>= 1) ss += __shfl_down(ss, off);
    ss = __shfl(ss, 0);
    float inv = 1.0f / (sqrtf(ss) + 1e-9f);
    size_t bbase = elem_off + (size_t)row * d;
    if (isb) {
        unsigned* o = (unsigned*)((bf16*)out + bbase);
        for (int j = 2 * lane; j < d; j += 128) {
            float2 x = a2[j >> 1];
            o[j >> 1] = f2b(x.x * inv) | (f2b(x.y * inv) << 16);
        }
    } else {
        float2* o = (float2*)((float*)out + bbase);
        for (int j = 2 * lane; j < d; j += 128) {
            float2 x = a2[j >> 1];
            o[j >> 1] = make_float2(x.x * inv, x.y * inv);
        }
    }
}

static inline int spmm_grid(int nE) { return (nE + 3) / 4; }
static inline int row_grid(int n)   { return (n + 3) / 4; }

// Fused per-phase CSR build for two matrices A,B sharing one cursor block.
static void build2(hipStream_t stream,
                   const int* rowsA, const int* colsA, const void* valsA, int nA, int nEA,
                   const int* rowsB, const int* colsB, const void* valsB, int nB, int nEB,
                   int* rpA, int* rpB, int* curAB, int2* pairsA, int2* pairsB,
                   const int* dflag) {
    int nE = nEA + nEB;
    hipMemsetAsync(curAB, 0, (size_t)(nA + nB) * 4, stream);
    hist2_kernel<<<(nE + 255) / 256, 256, 0, stream>>>(rowsA, nEA, rowsB, nEB, nA, curAB);
    scan2_kernel<<<1, 1024, 0, stream>>>(curAB, rpA, nA, curAB + nA, rpB, nB);
    copy2_kernel<<<(nA + nB + 255) / 256, 256, 0, stream>>>(rpA, rpB, nA, nB, curAB);
    scatter2_kernel<<<(nE + 255) / 256, 256, 0, stream>>>(
        rowsA, colsA, valsA, nEA, rowsB, colsB, valsB, nEB, nA, curAB, pairsA, pairsB, dflag);
}

extern "C" void kernel_launch(void* const* d_in, const int* in_sizes, int n_in,
                              void* d_out, int out_size, void* d_ws, size_t ws_size,
                              hipStream_t stream) {
    const void* f1   = d_in[0];
    const void* f2   = d_in[1];
    const void* f3   = d_in[2];
    const void* wemb = d_in[3];
    const int*  a11r = (const int*)d_in[4];
    const int*  a11c = (const int*)d_in[5];
    const void* a11v = d_in[6];
    const int*  a22r = (const int*)d_in[7];
    const int*  a22c = (const int*)d_in[8];
    const void* a22v = d_in[9];
    const int*  a33r = (const int*)d_in[10];
    const int*  a33c = (const int*)d_in[11];
    const void* a33v = d_in[12];
    const int*  a01r = (const int*)d_in[13];
    const int*  a01c = (const int*)d_in[14];
    const void* a01v = d_in[15];
    const int*  a02r = (const int*)d_in[16];
    const int*  a02c = (const int*)d_in[17];
    const void* a02v = d_in[18];
    const int*  a03r = (const int*)d_in[19];
    const int*  a03c = (const int*)d_in[20];
    const void* a03v = d_in[21];
    const void* W3   = d_in[22];
    const void* b3   = d_in[23];
    const void* W1_2 = d_in[24];
    const void* b1_2 = d_in[25];
    const void* W2_2 = d_in[26];
    const void* b2_2 = d_in[27];
    const void* W3_2 = d_in[28];
    const void* b3_2 = d_in[29];

    int*   dflag = (int*)d_ws;
    float* base  = (float*)d_ws + 16;       // buffers start 64 B in (sized for fp32 worst case)
    float* S0   = base;                     // 20000*128
    float* S1   = base + 2560000;           // 20000*128
    float* AGG1 = S1;                       // 10000*128 fp32 (S1 dead when used)
    float* E0   = base;                     // 10000*128
    float* E1   = base + 1280000;           // 10000*128
    float* AGG2 = base + 1280000;           // 10000*428 fp32 (E1 dead when used)
    float* P3a  = base;                     // 60*128
    float* P3b  = base + 7680;              // 60*128
    float* AGG3 = base + 15360;             // 10000*128 fp32

    // CSR region after dense peak: [rpA | rpB | curAB | pairsA | pairsB]
    int* I = (int*)(base + 5560000);
    const size_t WS_NEEDED = 64 + 22240000ull + 240008ull + 4960000ull; // ~27.44 MB

    const size_t OUT1_OFF = 0;
    const size_t OUT2_OFF = (size_t)N_DOC * DD;                       // 1,280,000
    const size_t OUT3_OFF = OUT2_OFF + (size_t)N_DOC * (DD + D_WEMB); // 5,560,000

    dim3 blk(256);
    detect_kernel<<<1, 256, 0, stream>>>((const unsigned*)f1, dflag);

    if (ws_size >= WS_NEEDED) {
        // ================= CSR gather path (bf16 intermediates when isb) =================
        // ---------------- type 1 (words): A=A11 (20000), B=A01 (10000) ----------------
        {
            int* rpA = I; int* rpB = rpA + (N_WORD + 1); int* cur = rpB + (N_DOC + 1);
            int2* pA = (int2*)(cur + N_WORD + N_DOC); int2* pB = pA + E11;
            build2(stream, a11r, a11c, a11v, N_WORD, E11,
                   a01r, a01c, a01v, N_DOC, E01, rpA, rpB, cur, pA, pB, dflag);
            spmm_gather<false, 128><<<row_grid(N_WORD), blk, 0, stream>>>(
                rpA, pA, f1, DD, 1, S0, DD, 0, 1, N_WORD, dflag);     // S0 = A11@f1
            gemm_tile<true><<<dim3((N_WORD + 63) / 64, 4), 256, 0, stream>>>(
                S0, W1_2, b1_2, S1, N_WORD, dflag);                   // S1 = relu(S0)@W+b
            spmm_gather<false, 128><<<row_grid(N_WORD), blk, 0, stream>>>(
                rpA, pA, S1, DD, 1, S0, DD, 0, 1, N_WORD, dflag);     // S0 = A11@S1
            spmm_gather<true, 128><<<row_grid(N_DOC), blk, 0, stream>>>(
                rpB, pB, S0, DD, 1, AGG1, DD, 0, 0, N_DOC, dflag);    // AGG1 = A01@relu(S0)
            l2norm_kernel<<<row_grid(N_DOC), blk, 0, stream>>>(
                AGG1, DD, d_out, OUT1_OFF, N_DOC, dflag);
        }
        // ---------------- type 2 (entities): A=A22 (10000), B=A02 (10000) ----------------
        {
            int* rpA = I; int* rpB = rpA + (N_ENT + 1); int* cur = rpB + (N_DOC + 1);
            int2* pA = (int2*)(cur + N_ENT + N_DOC); int2* pB = pA + E22;
            build2(stream, a22r, a22c, a22v, N_ENT, E22,
                   a02r, a02c, a02v, N_DOC, E02, rpA, rpB, cur, pA, pB, dflag);
            spmm_gather<false, 128><<<row_grid(N_ENT), blk, 0, stream>>>(
                rpA, pA, f2, DD, 1, E0, DD, 0, 1, N_ENT, dflag);      // E0 = A22@f2
            gemm_tile<true><<<dim3((N_ENT + 63) / 64, 4), 256, 0, stream>>>(
                E0, W2_2, b2_2, E1, N_ENT, dflag);                    // E1 = relu(E0)@W+b
            spmm_gather<false, 128><<<row_grid(N_ENT), blk, 0, stream>>>(
                rpA, pA, E1, DD, 1, E0, DD, 0, 1, N_ENT, dflag);      // E0 = A22@E1
            spmm_gather<true, 128><<<row_grid(N_DOC), blk, 0, stream>>>(
                rpB, pB, E0, DD, 1, AGG2, DD + D_WEMB, 0, 0, N_DOC, dflag);
            spmm_gather<false, 300><<<row_grid(N_DOC), blk, 0, stream>>>(
                rpB, pB, wemb, D_WEMB, 1, AGG2, DD + D_WEMB, DD, 0, N_DOC, dflag);
            l2norm_kernel<<<row_grid(N_DOC), blk, 0, stream>>>(
                AGG2, DD + D_WEMB, d_out, OUT2_OFF, N_DOC, dflag);
        }
        // ---------------- type 3 (POS): A=A33 (60), B=A03 (10000) ----------------
        {
            int* rpA = I; int* rpB = rpA + (N_POS + 1); int* cur = rpB + (N_DOC + 1);
            int2* pA = (int2*)(cur + N_POS + N_DOC); int2* pB = pA + E33;
            build2(stream, a33r, a33c, a33v, N_POS, E33,
                   a03r, a03c, a03v, N_DOC, E03, rpA, rpB, cur, pA, pB, dflag);
            rowpar_gemm<false, 60><<<N_POS, 128, 0, stream>>>(
                f3, 1, W3, b3, P3a, 1, dflag);                        // P3a = f3@W3+b3
            spmm_gather<false, 128><<<row_grid(N_POS), blk, 0, stream>>>(
                rpA, pA, P3a, DD, 1, P3b, DD, 0, 1, N_POS, dflag);    // P3b = A33@P3a
            rowpar_gemm<true, 128><<<N_POS, 128, 0, stream>>>(
                P3b, 1, W3_2, b3_2, P3a, 1, dflag);                   // P3a = relu(P3b)@W+b
            spmm_gather<false, 128><<<row_grid(N_POS), blk, 0, stream>>>(
                rpA, pA, P3a, DD, 1, P3b, DD, 0, 1, N_POS, dflag);    // P3b = A33@P3a
            spmm_gather<true, 128><<<row_grid(N_DOC), blk, 0, stream>>>(
                rpB, pB, P3b, DD, 1, AGG3, DD, 0, 0, N_DOC, dflag);   // AGG3 = A03@relu(P3b)
            l2norm_kernel<<<row_grid(N_DOC), blk, 0, stream>>>(
                AGG3, DD, d_out, OUT3_OFF, N_DOC, dflag);
        }
    } else {
        // ================= fallback: atomic-scatter path (fp32 ws) =================
        hipMemsetAsync(S0, 0, (size_t)N_WORD * DD * 4, stream);
        spmm_kernel<false><<<spmm_grid(E11), blk, 0, stream>>>(
            a11r, a11c, a11v, f1, DD, 1, S0, DD, 0, DD, E11, dflag);
        gemm128_kernel<true><<<(N_WORD + 63) / 64, 256, 0, stream>>>(
            S0, W1_2, b1_2, S1, N_WORD, dflag);
        hipMemsetAsync(S0, 0, (size_t)N_WORD * DD * 4, stream);
        spmm_kernel<false><<<spmm_grid(E11), blk, 0, stream>>>(
            a11r, a11c, a11v, S1, DD, 0, S0, DD, 0, DD, E11, dflag);
        hipMemsetAsync(AGG1, 0, (size_t)N_DOC * DD * 4, stream);
        spmm_kernel<true><<<spmm_grid(E01), blk, 0, stream>>>(
            a01r, a01c, a01v, S0, DD, 0, AGG1, DD, 0, DD, E01, dflag);
        l2norm_kernel<<<row_grid(N_DOC), blk, 0, stream>>>(
            AGG1, DD, d_out, OUT1_OFF, N_DOC, dflag);

        hipMemsetAsync(E0, 0, (size_t)N_ENT * DD * 4, stream);
        spmm_kernel<false><<<spmm_grid(E22), blk, 0, stream>>>(
            a22r, a22c, a22v, f2, DD, 1, E0, DD, 0, DD, E22, dflag);
        gemm128_kernel<true><<<(N_ENT + 63) / 64, 256, 0, stream>>>(
            E0, W2_2, b2_2, E1, N_ENT, dflag);
        hipMemsetAsync(E0, 0, (size_t)N_ENT * DD * 4, stream);
        spmm_kernel<false><<<spmm_grid(E22), blk, 0, stream>>>(
            a22r, a22c, a22v, E1, DD, 0, E0, DD, 0, DD, E22, dflag);
        hipMemsetAsync(AGG2, 0, (size_t)N_DOC * (DD + D_WEMB) * 4, stream);
        spmm_kernel<true><<<spmm_grid(E02), blk, 0, stream>>>(
            a02r, a02c, a02v, E0, DD, 0, AGG2, DD + D_WEMB, 0, DD, E02, dflag);
        spmm_kernel<false><<<spmm_grid(E02), blk, 0, stream>>>(
            a02r, a02c, a02v, wemb, D_WEMB, 1, AGG2, DD + D_WEMB, DD, D_WEMB, E02, dflag);
        l2norm_kernel<<<row_grid(N_DOC), blk, 0, stream>>>(
            AGG2, DD + D_WEMB, d_out, OUT2_OFF, N_DOC, dflag);

        gemm_kernel<false, 60><<<1, 128, 0, stream>>>(f3, 1, W3, b3, P3a, N_POS, dflag);
        hipMemsetAsync(P3b, 0, (size_t)N_POS * DD * 4, stream);
        spmm_kernel<false><<<spmm_grid(E33), blk, 0, stream>>>(
            a33r, a33c, a33v, P3a, DD, 0, P3b, DD, 0, DD, E33, dflag);
        gemm128_kernel<true><<<1, 256, 0, stream>>>(
            P3b, W3_2, b3_2, P3a, N_POS, dflag);
        hipMemsetAsync(P3b, 0, (size_t)N_POS * DD * 4, stream);
        spmm_kernel<false><<<spmm_grid(E33), blk, 0, stream>>>(
            a33r, a33c, a33v, P3a, DD, 0, P3b, DD, 0, DD, E33, dflag);
        hipMemsetAsync(AGG3, 0, (size_t)N_DOC * DD * 4, stream);
        spmm_kernel<true><<<spmm_grid(E03), blk, 0, stream>>>(
            a03r, a03c, a03v, P3b, DD, 0, AGG3, DD, 0, DD, E03, dflag);
        l2norm_kernel<<<row_grid(N_DOC), blk, 0, stream>>>(
            AGG3, DD, d_out, OUT3_OFF, N_DOC, dflag);
    }
}